// Round 7
// baseline (180.156 us; speedup 1.0000x reference)
//
#include <hip/hip_runtime.h>

#define DM    128
#define DI    256
#define NH    8
#define HD    32
#define NS    64
#define CDIM  384
#define DPROJ 648
#define LSEQ  4096
#define NB    8
#define NTOK  32768          // NB*LSEQ
#define LC    64             // chunk length
#define NC    64             // chunks per (b,h) sequence
#define EPSF  1e-5f
#define LOG2E 1.4426950408889634f

typedef __bf16 bf16;
typedef bf16  bf16x8 __attribute__((ext_vector_type(8)));
typedef bf16  bf16x4 __attribute__((ext_vector_type(4)));
typedef short short8 __attribute__((ext_vector_type(8)));
typedef float f32x4  __attribute__((ext_vector_type(4)));

__device__ __forceinline__ unsigned short f2bfbits(float f) {
    unsigned int u = __float_as_uint(f);
    unsigned int r = u + 0x7FFFu + ((u >> 16) & 1u);   // RNE
    return (unsigned short)(r >> 16);
}
__device__ __forceinline__ float bfbits2f(unsigned short u) {
    return __uint_as_float(((unsigned int)u) << 16);
}

// ---------------- 0. prep: W1 + W2 fragment-packs (gnorm folded into W2) -------
__global__ __launch_bounds__(256) void k_prep(const float* __restrict__ w1,
                                              const float* __restrict__ w2,
                                              const float* __restrict__ gw,
                                              unsigned short* __restrict__ w1g,
                                              unsigned short* __restrict__ w2f) {
    int i = blockIdx.x * 256 + threadIdx.x;
    if (i < 640 * DM) {
        int f = i >> 9, r = i & 511;
        int lane = r >> 3, jj = r & 7;
        int ns = f >> 2, kk = f & 3;
        int n = ns * 16 + (lane & 15), k = kk * 32 + (lane >> 4) * 8 + jj;
        w1g[i] = f2bfbits(w1[(size_t)n * DM + k]);
    } else {
        int j = i - 640 * DM;
        if (j < DM * DI) {
            int f = j >> 9, r = j & 511;
            int lane = r >> 3, jj = r & 7;
            int kk = f >> 3, nt = f & 7;
            int fr = lane & 15, ko = lane >> 4;
            int n = nt * 16 + fr, k = kk * 32 + ko * 8 + jj;
            w2f[j] = f2bfbits(w2[(size_t)n * DI + k] * gw[k]);
        }
    }
}

// ---------------- FRONT: rmsnorm + dt + GEMM1 + conv + ssd1, one chunk/block ---
// 512 threads = 8 waves. LDS hand-laid with aliasing:
//   [0      .. 62720)  XBC  [80][392] bf16  (16 halo rows + 64 own, xBC cols)
//   [62720  ..108800)  Xs   [80][132] f32 (phases 1-2)  ALIAS  Lc [320][72] bf16 (conv out)
//   [108800 ..113024)  Wd   [8][132] f32   (dt weight rows)
//   [113024 ..115072)  dts  [64][8]  f32   (dt per token,head)
//   [115072 ..117120)  wlh  [8][64]  f32   (ssd1 decay weights)
// Halo xBC (tokens t0-3..t0-1) recomputed via one extra 16-row m-frag in the
// GEMM (xBC cols only, wm==0 waves); unused (garbage OK) when l0==0.
__global__ __launch_bounds__(512) void k_front(const float* __restrict__ x,
                                               const float* __restrict__ nw,
                                               const float* __restrict__ w1,
                                               const float* __restrict__ dtb,
                                               const unsigned short* __restrict__ w1g,
                                               const float* __restrict__ cw,
                                               const float* __restrict__ cb,
                                               const float* __restrict__ alog,
                                               unsigned short* __restrict__ zb,
                                               float* __restrict__ dtf,
                                               unsigned short* __restrict__ bcA,
                                               unsigned short* __restrict__ xT,
                                               unsigned short* __restrict__ hst,
                                               float* __restrict__ dAp) {
    __shared__ __align__(16) unsigned char SMEM[117120];
    unsigned short* XBC = (unsigned short*)SMEM;             // [80][392]
    float*          Xs  = (float*)(SMEM + 62720);            // [80][132]
    unsigned short* Lc  = (unsigned short*)(SMEM + 62720);   // [320][72] (alias Xs)
    float*          Wd  = (float*)(SMEM + 108800);           // [8][132]
    float*          dts = (float*)(SMEM + 113024);           // [64][8]
    float*          wlh = (float*)(SMEM + 115072);           // [8][64]
    const int tid = threadIdx.x;
    const int wave = tid >> 6, lane = tid & 63;
    const int t0 = blockIdx.x * 64;
    const int l0 = t0 & (LSEQ - 1);
    // stage dt weight rows
    if (tid < 256) {
        int row = tid >> 5, col = (tid & 31) * 4;
        *(float4*)&Wd[row * 132 + col] = *(const float4*)(w1 + (size_t)(640 + row) * DM + col);
    }
    // --- phase 1: rmsnorm 80 rows (16 halo + 64 own) -> fp32 Xs ---
    const float nw0 = nw[lane * 2], nw1 = nw[lane * 2 + 1];
    #pragma unroll
    for (int i = 0; i < 10; i++) {
        int r = wave * 10 + i;
        int tok = t0 + r - 16; if (tok < 0) tok = 0;     // clamp (unused when l0==0)
        const float* xr = x + (size_t)tok * DM + lane * 2;
        float v0 = xr[0], v1 = xr[1];
        float ss = v0 * v0 + v1 * v1;
        #pragma unroll
        for (int o = 32; o; o >>= 1) ss += __shfl_xor(ss, o);
        float rs = rsqrtf(ss * (1.0f / DM) + EPSF);
        Xs[r * 132 + lane * 2]     = v0 * rs * nw0;
        Xs[r * 132 + lane * 2 + 1] = v1 * rs * nw1;
    }
    __syncthreads();
    // --- phase 2a: dt (fp32 exact), 8 own rows per wave ---
    {
        const int h = lane >> 3, ks = lane & 7;
        const float dtbh = dtb[h];
        #pragma unroll
        for (int i = 0; i < 8; i++) {
            int rw = wave * 8 + i;              // own-token index 0..63
            int r = 16 + rw;
            float acc = 0.f;
            #pragma unroll
            for (int q = 0; q < 4; q++) {
                float4 xv = *(const float4*)&Xs[r * 132 + ks * 16 + q * 4];
                float4 wv = *(const float4*)&Wd[h * 132 + ks * 16 + q * 4];
                acc = fmaf(xv.x, wv.x, acc); acc = fmaf(xv.y, wv.y, acc);
                acc = fmaf(xv.z, wv.z, acc); acc = fmaf(xv.w, wv.w, acc);
            }
            acc += __shfl_xor(acc, 1);
            acc += __shfl_xor(acc, 2);
            acc += __shfl_xor(acc, 4);
            if (ks == 0) {
                float v = acc + dtbh;
                float sp = (v > 20.f) ? v : log1pf(expf(v));
                dtf[(size_t)(t0 + rw) * NH + h] = sp;
                dts[rw * NH + h] = sp;
            }
        }
    }
    // --- phase 2b: bf16 A-frags (own 2, halo 1) from Xs ---
    const int wm = wave >> 2, wn = wave & 3;
    const int fr = lane & 15, ko = lane >> 4;
    bf16x8 a0[4], a1[4], ah[4];
    #pragma unroll
    for (int kk = 0; kk < 4; kk++) {
        const float* s0 = &Xs[(16 + wm * 32 + fr) * 132 + kk * 32 + ko * 8];
        const float* s1 = &Xs[(16 + wm * 32 + 16 + fr) * 132 + kk * 32 + ko * 8];
        const float* sh = &Xs[fr * 132 + kk * 32 + ko * 8];
        bf16x8 f0, f1, fh;
        #pragma unroll
        for (int j = 0; j < 8; j++) {
            f0[j] = (bf16)s0[j]; f1[j] = (bf16)s1[j]; fh[j] = (bf16)sh[j];
        }
        a0[kk] = f0; a1[kk] = f1; ah[kk] = fh;
    }
    // --- GEMM: 10 n-frags per wave (round-robin over wn); B = 1KB wave loads ---
    for (int i = 0; i < 10; i++) {
        int f = i * 4 + wn;
        const unsigned short* wb = w1g + (((size_t)f * 4) << 9) + lane * 8;
        f32x4 acc0 = {}, acc1 = {}, accH = {};
        #pragma unroll
        for (int kk = 0; kk < 4; kk++) {
            bf16x8 bfr = *(const bf16x8*)(wb + ((size_t)kk << 9));
            acc0 = __builtin_amdgcn_mfma_f32_16x16x32_bf16(a0[kk], bfr, acc0, 0, 0, 0);
            acc1 = __builtin_amdgcn_mfma_f32_16x16x32_bf16(a1[kk], bfr, acc1, 0, 0, 0);
            if (i >= 4 && wm == 0)
                accH = __builtin_amdgcn_mfma_f32_16x16x32_bf16(ah[kk], bfr, accH, 0, 0, 0);
        }
        if (i < 4) {                     // z frag -> global
            int n = f * 16 + fr;
            #pragma unroll
            for (int rr = 0; rr < 4; rr++) {
                zb[(size_t)(t0 + wm * 32 + ko * 4 + rr) * DI + n]      = f2bfbits(acc0[rr]);
                zb[(size_t)(t0 + wm * 32 + 16 + ko * 4 + rr) * DI + n] = f2bfbits(acc1[rr]);
            }
        } else {                         // xBC frag -> LDS
            int cc = f * 16 + fr - 256;
            #pragma unroll
            for (int rr = 0; rr < 4; rr++) {
                XBC[(16 + wm * 32 + ko * 4 + rr) * 392 + cc]      = f2bfbits(acc0[rr]);
                XBC[(16 + wm * 32 + 16 + ko * 4 + rr) * 392 + cc] = f2bfbits(acc1[rr]);
            }
            if (wm == 0) {
                #pragma unroll
                for (int rr = 0; rr < 4; rr++)
                    XBC[(ko * 4 + rr) * 392 + cc] = f2bfbits(accH[rr]);
            }
        }
    }
    __syncthreads();                     // XBC complete; Xs dead (Lc may now alias)
    // --- conv phase: K=4 causal + SiLU, channel per thread, inputs from LDS ---
    if (tid < CDIM) {
        const int ch = tid;
        float4 wv = *(const float4*)(cw + ch * 4);
        float bias = cb[ch];
        float h1 = 0.f, h2 = 0.f, h3 = 0.f;
        if (l0) {
            h1 = bfbits2f(XBC[15 * 392 + ch]);
            h2 = bfbits2f(XBC[14 * 392 + ch]);
            h3 = bfbits2f(XBC[13 * 392 + ch]);
        }
        short8 pk;
        #pragma unroll 8
        for (int t = 0; t < 64; t++) {
            float x0 = bfbits2f(XBC[(16 + t) * 392 + ch]);
            float acc = bias;
            acc = fmaf(x0, wv.w, acc);
            acc = fmaf(h1, wv.z, acc);
            acc = fmaf(h2, wv.y, acc);
            acc = fmaf(h3, wv.x, acc);
            float s = acc / (1.f + expf(-acc));
            unsigned short us = f2bfbits(s);
            if (ch >= 256) bcA[(size_t)(t0 + t) * 128 + (ch - 256)] = us;  // B|C tok-major
            pk[t & 7] = (short)us;
            if (ch < 320 && (t & 7) == 7) *(short8*)&Lc[ch * 72 + t - 7] = pk;
            h3 = h2; h2 = h1; h1 = x0;
        }
    }
    __syncthreads();
    // --- xT writeout (x channels, for ssd3g) ---
    {
        int idx = tid;
        #pragma unroll
        for (int it = 0; it < 4; it++, idx += 512) {
            int row = idx >> 3, tc = (idx & 7) * 8;
            *(short8*)(xT + (size_t)row * NTOK + t0 + tc) = *(const short8*)&Lc[row * 72 + tc];
        }
    }
    // --- ssd1 phase: wave = head, chunk-local end state ---
    {
        const int h = wave;
        const int b = blockIdx.x >> 6, c = blockIdx.x & 63;
        const int bh = b * NH + h;
        const float A = -expf(alog[h]);
        float dt = dts[lane * NH + h];
        float q = dt * A * LOG2E;
        #pragma unroll
        for (int o = 1; o <= 32; o <<= 1) {
            float tmp = __shfl_up(q, o);
            if (lane >= o) q += tmp;
        }
        float qL = __shfl(q, 63);
        wlh[h * 64 + lane] = exp2f(qL - q) * dt;   // intra-wave LDS: no barrier
        if (lane == 0) dAp[(size_t)bh * NC + c] = exp2f(qL);
        const int m = lane & 15;
        f32x4 hacc[4][2] = {};
        #pragma unroll
        for (int kh = 0; kh < 2; kh++) {
            bf16x8 xb[2];
            #pragma unroll
            for (int pi = 0; pi < 2; pi++)
                xb[pi] = *(const bf16x8*)&Lc[(h * HD + pi * 16 + m) * 72 + kh * 32 + ko * 8];
            f32x4 w0 = *(const f32x4*)&wlh[h * 64 + kh * 32 + ko * 8];
            f32x4 w1v = *(const f32x4*)&wlh[h * 64 + kh * 32 + ko * 8 + 4];
            #pragma unroll
            for (int ni = 0; ni < 4; ni++) {
                bf16x8 bv = *(const bf16x8*)&Lc[(256 + ni * 16 + m) * 72 + kh * 32 + ko * 8];
                bf16x8 af;
                #pragma unroll
                for (int j = 0; j < 4; j++) af[j] = (bf16)((float)bv[j] * w0[j]);
                #pragma unroll
                for (int j = 0; j < 4; j++) af[4 + j] = (bf16)((float)bv[4 + j] * w1v[j]);
                #pragma unroll
                for (int pi = 0; pi < 2; pi++)
                    hacc[ni][pi] = __builtin_amdgcn_mfma_f32_16x16x32_bf16(af, xb[pi], hacc[ni][pi], 0, 0, 0);
            }
        }
        unsigned short* hb = hst + (((size_t)bh * NC + c) << 11);
        #pragma unroll
        for (int ni = 0; ni < 4; ni++)
            #pragma unroll
            for (int pi = 0; pi < 2; pi++) {
                bf16x4 pv;
                #pragma unroll
                for (int r = 0; r < 4; r++) pv[r] = (bf16)hacc[ni][pi][r];
                *(bf16x4*)(hb + (pi * 16 + m) * 64 + ni * 16 + ko * 4) = pv;
            }
    }
}

// ---------------- 5b. SSM pass 2: scan, 1 bh/block, depth-4 load pipeline ------
__global__ __launch_bounds__(256) void k_ssm2(unsigned short* __restrict__ hst,
                                              const float* __restrict__ dAp) {
    __shared__ float dl[NC];
    const int bh = blockIdx.x >> 3, seg = blockIdx.x & 7;
    const int s = seg * 256 + threadIdx.x;
    if (threadIdx.x < NC) dl[threadIdx.x] = dAp[(size_t)bh * NC + threadIdx.x];
    __syncthreads();
    unsigned short* p = hst + ((size_t)bh * NC << 11) + s;
    float r = 0.f;
    float v0 = bfbits2f(p[0]);
    float v1 = bfbits2f(p[(size_t)1 << 11]);
    float v2 = bfbits2f(p[(size_t)2 << 11]);
    float v3 = bfbits2f(p[(size_t)3 << 11]);
    for (int c = 0; c < NC; c += 4) {
        float t;
        t = v0; if (c + 4 < NC) v0 = bfbits2f(p[(size_t)(c + 4) << 11]);
        p[(size_t)c << 11] = f2bfbits(r);       r = fmaf(r, dl[c], t);
        t = v1; if (c + 5 < NC) v1 = bfbits2f(p[(size_t)(c + 5) << 11]);
        p[(size_t)(c + 1) << 11] = f2bfbits(r); r = fmaf(r, dl[c + 1], t);
        t = v2; if (c + 6 < NC) v2 = bfbits2f(p[(size_t)(c + 6) << 11]);
        p[(size_t)(c + 2) << 11] = f2bfbits(r); r = fmaf(r, dl[c + 2], t);
        t = v3; if (c + 7 < NC) v3 = bfbits2f(p[(size_t)(c + 7) << 11]);
        p[(size_t)(c + 3) << 11] = f2bfbits(r); r = fmaf(r, dl[c + 3], t);
    }
}

// ---------------- 5c+6+7. fused SSD pass 3 + gate + GEMM2 + residual -----------
__global__ __launch_bounds__(512, 2) void k_ssd3g(const unsigned short* __restrict__ bcA,
                                                  const unsigned short* __restrict__ xT,
                                                  const float* __restrict__ dtf,
                                                  const float* __restrict__ alog,
                                                  const unsigned short* __restrict__ hst,
                                                  const float* __restrict__ Dw,
                                                  const unsigned short* __restrict__ zb,
                                                  const unsigned short* __restrict__ w2f,
                                                  const float* __restrict__ xin,
                                                  float* __restrict__ out) {
    __shared__ __align__(16) unsigned short BC[64][136];   // B|C chunk, all heads
    __shared__ __align__(16) bf16 PlY[NH][64 * 40];        // per-wave P half; alias: Ys[64][264]
    __shared__ float ql[NH][64];
    __shared__ float dl[NH][64];
    const int tid = threadIdx.x;
    const int b = blockIdx.x >> 6, c = blockIdx.x & 63;
    const int t0 = blockIdx.x * 64;
    const size_t tok0 = (size_t)t0;
    {
        int idx = tid;
        #pragma unroll
        for (int it = 0; it < 2; it++, idx += 512) {
            int tok = idx >> 4, c8 = (idx & 15) * 8;
            *(short8*)&BC[tok][c8] = *(const short8*)(bcA + (tok0 + tok) * 128 + c8);
        }
    }
    __syncthreads();
    const int h = tid >> 6, lane = tid & 63;
    const int bh = b * NH + h;
    const float A = -expf(alog[h]);
    const float Dh = Dw[h];
    float dt = dtf[(tok0 + lane) * NH + h];
    float q = dt * A * LOG2E;
    #pragma unroll
    for (int o = 1; o <= 32; o <<= 1) {
        float tmp = __shfl_up(q, o);
        if (lane >= o) q += tmp;
    }
    ql[h][lane] = q;                           // intra-wave LDS, no barrier
    dl[h][lane] = dt;
    const int m = lane & 15, ko = lane >> 4;
    bf16* Pw = &PlY[h][0];
    bf16x8 cf[4][2];
    #pragma unroll
    for (int ti = 0; ti < 4; ti++)
        #pragma unroll
        for (int kh = 0; kh < 2; kh++)
            cf[ti][kh] = *(const bf16x8*)&BC[ti * 16 + m][64 + kh * 32 + ko * 8];
    float qt[4];
    #pragma unroll
    for (int ti = 0; ti < 4; ti++) qt[ti] = ql[h][ti * 16 + m];
    const size_t hbase = ((size_t)bh * NC + c) << 11;
    f32x4 ya[4][2] = {}, ua[4][2] = {};
    #pragma unroll
    for (int kh = 0; kh < 2; kh++) {
        bf16x8 hb2[2];
        #pragma unroll
        for (int pi = 0; pi < 2; pi++)
            hb2[pi] = *(const bf16x8*)(hst + hbase + (pi * 16 + m) * 64 + kh * 32 + ko * 8);
        #pragma unroll
        for (int ti = 0; ti < 4; ti++)
            #pragma unroll
            for (int pi = 0; pi < 2; pi++)
                ua[ti][pi] = __builtin_amdgcn_mfma_f32_16x16x32_bf16(cf[ti][kh], hb2[pi], ua[ti][pi], 0, 0, 0);
    }
    #pragma unroll
    for (int sh = 0; sh < 2; sh++) {
        f32x4 gth[4][2] = {};
        #pragma unroll
        for (int kh = 0; kh < 2; kh++) {
            bf16x8 bfg[2];
            #pragma unroll
            for (int sj = 0; sj < 2; sj++)
                bfg[sj] = *(const bf16x8*)&BC[(sh * 2 + sj) * 16 + m][kh * 32 + ko * 8];
            #pragma unroll
            for (int ti = 0; ti < 4; ti++)
                #pragma unroll
                for (int sj = 0; sj < 2; sj++)
                    gth[ti][sj] = __builtin_amdgcn_mfma_f32_16x16x32_bf16(bfg[sj], cf[ti][kh], gth[ti][sj], 0, 0, 0);
        }
        #pragma unroll
        for (int sj = 0; sj < 2; sj++) {
            const int si = sh * 2 + sj;
            f32x4 qs = *(const f32x4*)&ql[h][si * 16 + ko * 4];
            f32x4 ds = *(const f32x4*)&dl[h][si * 16 + ko * 4];
            #pragma unroll
            for (int ti = 0; ti < 4; ti++) {
                bf16x4 pv = {};
                if (si <= ti) {
                    const int t = ti * 16 + m;
                    #pragma unroll
                    for (int r = 0; r < 4; r++) {
                        int s = si * 16 + ko * 4 + r;
                        float p = 0.f;
                        if (s <= t) {
                            p = exp2f(qt[ti] - qs[r]) * ds[r] * gth[ti][sj][r];
                            if (s == t) p += Dh;
                        }
                        pv[r] = (bf16)p;
                    }
                }
                *(bf16x4*)&Pw[(ti * 16 + m) * 40 + sj * 16 + ko * 4] = pv;
            }
        }
        bf16x8 xb[2];
        #pragma unroll
        for (int pi = 0; pi < 2; pi++)
            xb[pi] = *(const bf16x8*)(xT + (size_t)(h * HD + pi * 16 + m) * NTOK + tok0 + sh * 32 + ko * 8);
        #pragma unroll
        for (int ti = 0; ti < 4; ti++) {
            bf16x8 pa = *(const bf16x8*)&Pw[(ti * 16 + m) * 40 + ko * 8];
            #pragma unroll
            for (int pi = 0; pi < 2; pi++)
                ya[ti][pi] = __builtin_amdgcn_mfma_f32_16x16x32_bf16(pa, xb[pi], ya[ti][pi], 0, 0, 0);
        }
    }
    __syncthreads();
    unsigned short* Ys = (unsigned short*)&PlY[0][0];    // [64][264]
    {
        f32x4 et[4];
        #pragma unroll
        for (int ti = 0; ti < 4; ti++) {
            f32x4 qv = *(const f32x4*)&ql[h][ti * 16 + ko * 4];
            #pragma unroll
            for (int r = 0; r < 4; r++) et[ti][r] = exp2f(qv[r]);
        }
        #pragma unroll
        for (int ti = 0; ti < 4; ti++)
            #pragma unroll
            for (int pi = 0; pi < 2; pi++)
                #pragma unroll
                for (int r = 0; r < 4; r++) {
                    int t = ti * 16 + ko * 4 + r;
                    Ys[t * 264 + h * HD + pi * 16 + m] =
                        f2bfbits(ya[ti][pi][r] + et[ti][r] * ua[ti][pi][r]);
                }
    }
    __syncthreads();
    {
        const int rg = h & 3, nh = h >> 2;
        const int r0 = rg * 16;
        const size_t rowo = (tok0 + r0 + m) * DI;
        float ss = 0.f;
        bf16x8 gb[8];
        #pragma unroll
        for (int kk = 0; kk < 8; kk++) {
            int co = kk * 32 + ko * 8;
            bf16x8 yv = *(const bf16x8*)&Ys[(r0 + m) * 264 + co];
            bf16x8 zv = *(const bf16x8*)(zb + rowo + co);
            #pragma unroll
            for (int j = 0; j < 8; j++) {
                float z = (float)zv[j];
                float g = (float)yv[j] * (z / (1.f + expf(-z)));
                ss += g * g;
                gb[kk][j] = (bf16)g;
            }
        }
        ss += __shfl_xor(ss, 16);
        ss += __shfl_xor(ss, 32);
        const float rs = rsqrtf(ss * (1.0f / DI) + EPSF);
        #pragma unroll
        for (int kk = 0; kk < 8; kk++)
            #pragma unroll
            for (int j = 0; j < 8; j++)
                gb[kk][j] = (bf16)((float)gb[kk][j] * rs);
        const unsigned short* wp = w2f + (size_t)lane * 8;
        f32x4 acc[4] = {};
        #pragma unroll
        for (int kk = 0; kk < 8; kk++) {
            #pragma unroll
            for (int ntl = 0; ntl < 4; ntl++) {
                bf16x8 bfr = *(const bf16x8*)(wp + (((size_t)kk * 8 + nh * 4 + ntl) << 9));
                acc[ntl] = __builtin_amdgcn_mfma_f32_16x16x32_bf16(gb[kk], bfr, acc[ntl], 0, 0, 0);
            }
        }
        #pragma unroll
        for (int ntl = 0; ntl < 4; ntl++) {
            int n = (nh * 4 + ntl) * 16 + m;
            #pragma unroll
            for (int rr = 0; rr < 4; rr++) {
                size_t row = tok0 + r0 + ko * 4 + rr;
                out[row * DM + n] = xin[row * DM + n] + acc[ntl][rr];
            }
        }
    }
}

extern "C" void kernel_launch(void* const* d_in, const int* in_sizes, int n_in,
                              void* d_out, int out_size, void* d_ws, size_t ws_size,
                              hipStream_t stream) {
    const float* x   = (const float*)d_in[0];
    const float* nw  = (const float*)d_in[1];
    const float* w1  = (const float*)d_in[2];
    const float* cw  = (const float*)d_in[3];
    const float* cb  = (const float*)d_in[4];
    const float* dtb = (const float*)d_in[5];
    const float* al  = (const float*)d_in[6];
    const float* Dw  = (const float*)d_in[7];
    const float* gw  = (const float*)d_in[8];
    const float* w2  = (const float*)d_in[9];
    float* out = (float*)d_out;

    float* ws = (float*)d_ws;
    float*  dAp = ws;                                   // 4096 fp32
    float*  dtf = dAp + NB * NH * NC;                   // NTOK*8 fp32
    unsigned short* hst = (unsigned short*)(dtf + (size_t)NTOK * NH); // 64*64*2048 bf16
    unsigned short* zb  = hst + (size_t)NB * NH * NC * 2048;          // NTOK*256
    unsigned short* bcA = zb + (size_t)NTOK * DI;                     // NTOK*128 (B|C tok-major)
    unsigned short* xT  = bcA + (size_t)NTOK * 128;                   // 256*NTOK (x ch-major)
    unsigned short* w1g = xT + (size_t)DI * NTOK;                     // 640*128 frag-packed
    unsigned short* w2f = w1g + (size_t)640 * DM;                     // 128*256 frag-packed

    k_prep<<<(640 * DM + DM * DI + 255) / 256, 256, 0, stream>>>(w1, w2, gw, w1g, w2f);
    k_front<<<NTOK / 64, 512, 0, stream>>>(x, nw, w1, dtb, w1g, cw, cb, al,
                                           zb, dtf, bcA, xT, hst, dAp);
    k_ssm2<<<NB * NH * 8, 256, 0, stream>>>(hst, dAp);
    k_ssd3g<<<NTOK / 64, 512, 0, stream>>>(bcA, xT, dtf, al, hst, Dw, zb, w2f, x, out);
}

// Round 8
// 165.208 us; speedup vs baseline: 1.0905x; 1.0905x over previous
//
#include <hip/hip_runtime.h>

#define DM    128
#define DI    256
#define NH    8
#define HD    32
#define NS    64
#define CDIM  384
#define DPROJ 648
#define LSEQ  4096
#define NB    8
#define NTOK  32768          // NB*LSEQ
#define LC    64             // chunk length
#define NC    64             // chunks per (b,h) sequence
#define EPSF  1e-5f
#define LOG2E 1.4426950408889634f

typedef __bf16 bf16;
typedef bf16  bf16x8 __attribute__((ext_vector_type(8)));
typedef bf16  bf16x4 __attribute__((ext_vector_type(4)));
typedef short short8 __attribute__((ext_vector_type(8)));
typedef float f32x4  __attribute__((ext_vector_type(4)));

__device__ __forceinline__ unsigned short f2bfbits(float f) {
    unsigned int u = __float_as_uint(f);
    unsigned int r = u + 0x7FFFu + ((u >> 16) & 1u);   // RNE
    return (unsigned short)(r >> 16);
}
__device__ __forceinline__ float bfbits2f(unsigned short u) {
    return __uint_as_float(((unsigned int)u) << 16);
}

// ---------------- 0. prep: W1 + W2 fragment-packs (gnorm folded into W2) -------
__global__ __launch_bounds__(256) void k_prep(const float* __restrict__ w1,
                                              const float* __restrict__ w2,
                                              const float* __restrict__ gw,
                                              unsigned short* __restrict__ w1g,
                                              unsigned short* __restrict__ w2f) {
    int i = blockIdx.x * 256 + threadIdx.x;
    if (i < 640 * DM) {
        int f = i >> 9, r = i & 511;
        int lane = r >> 3, jj = r & 7;
        int ns = f >> 2, kk = f & 3;
        int n = ns * 16 + (lane & 15), k = kk * 32 + (lane >> 4) * 8 + jj;
        w1g[i] = f2bfbits(w1[(size_t)n * DM + k]);
    } else {
        int j = i - 640 * DM;
        if (j < DM * DI) {
            int f = j >> 9, r = j & 511;
            int lane = r >> 3, jj = r & 7;
            int kk = f >> 3, nt = f & 7;
            int fr = lane & 15, ko = lane >> 4;
            int n = nt * 16 + fr, k = kk * 32 + ko * 8 + jj;
            w2f[j] = f2bfbits(w2[(size_t)n * DI + k] * gw[k]);
        }
    }
}

// ---------------- FRONT v2: rmsnorm + dt + GEMM1 + conv + ssd1, 64KB LDS -------
// LDS (64 KB total -> 2 blocks/CU):
//   [0     ..33792)  Xs  [64][132] f32 (own rmsnorm rows; phases 1-2)
//                    ALIAS (phase 3+): XT [384][80] bf16, channel-major xBC
//                    (cols 4..7 = halo tokens t0-4..t0-1, cols 8..71 = own)
//   [33792 ..38144)  Hb  [16][136] bf16 (halo rmsnorm rows; phases 1-2, under XT)
//   [38144 ..42368)  Wd  [8][132]  f32  (dt weight rows; phases 1-2, under XT)
//   [61440 ..63488)  dts [64][8]   f32  (persistent)
//   [63488 ..65536)  wlh [8][64]   f32  (persistent)
// Conv is register-resident: row load 8xb128+1xb64, conv in regs, write back.
__global__ __launch_bounds__(512, 4) void k_front(const float* __restrict__ x,
                                                  const float* __restrict__ nw,
                                                  const float* __restrict__ w1,
                                                  const float* __restrict__ dtb,
                                                  const unsigned short* __restrict__ w1g,
                                                  const float* __restrict__ cw,
                                                  const float* __restrict__ cb,
                                                  const float* __restrict__ alog,
                                                  unsigned short* __restrict__ zb,
                                                  float* __restrict__ dtf,
                                                  unsigned short* __restrict__ bcA,
                                                  unsigned short* __restrict__ xTg,
                                                  unsigned short* __restrict__ hst,
                                                  float* __restrict__ dAp) {
    __shared__ __align__(16) unsigned char SMEM[65536];
    float*          Xs  = (float*)SMEM;                    // [64][132]
    unsigned short* XT  = (unsigned short*)SMEM;           // [384][80] (alias)
    unsigned short* Hb  = (unsigned short*)(SMEM + 33792); // [16][136]
    float*          Wd  = (float*)(SMEM + 38144);          // [8][132]
    float*          dts = (float*)(SMEM + 61440);          // [64][8]
    float*          wlh = (float*)(SMEM + 63488);          // [8][64]
    const int tid = threadIdx.x;
    const int wave = tid >> 6, lane = tid & 63;
    const int t0 = blockIdx.x * 64;
    const int l0 = t0 & (LSEQ - 1);
    // stage dt weight rows (fp32)
    if (tid < 256) {
        int row = tid >> 5, col = (tid & 31) * 4;
        *(float4*)&Wd[row * 132 + col] = *(const float4*)(w1 + (size_t)(640 + row) * DM + col);
    }
    // --- phase 1: rmsnorm 80 rows; halo -> bf16 Hb, own -> fp32 Xs ---
    const float nw0 = nw[lane * 2], nw1 = nw[lane * 2 + 1];
    #pragma unroll
    for (int i = 0; i < 10; i++) {
        int r = wave * 10 + i;
        int tok = t0 + r - 16; if (tok < 0) tok = 0;    // clamp (unused when l0==0)
        const float* xr = x + (size_t)tok * DM + lane * 2;
        float v0 = xr[0], v1 = xr[1];
        float ss = v0 * v0 + v1 * v1;
        #pragma unroll
        for (int o = 32; o; o >>= 1) ss += __shfl_xor(ss, o);
        float rs = rsqrtf(ss * (1.0f / DM) + EPSF);
        float o0 = v0 * rs * nw0, o1 = v1 * rs * nw1;
        if (r < 16) {
            ushort2 hb; hb.x = f2bfbits(o0); hb.y = f2bfbits(o1);
            *(ushort2*)&Hb[r * 136 + lane * 2] = hb;
        } else {
            Xs[(r - 16) * 132 + lane * 2]     = o0;
            Xs[(r - 16) * 132 + lane * 2 + 1] = o1;
        }
    }
    __syncthreads();
    // --- phase 2a: dt (fp32 exact), 8 own rows per wave ---
    {
        const int h = lane >> 3, ks = lane & 7;
        const float dtbh = dtb[h];
        #pragma unroll
        for (int i = 0; i < 8; i++) {
            int rw = wave * 8 + i;
            float acc = 0.f;
            #pragma unroll
            for (int q = 0; q < 4; q++) {
                float4 xv = *(const float4*)&Xs[rw * 132 + ks * 16 + q * 4];
                float4 wv = *(const float4*)&Wd[h * 132 + ks * 16 + q * 4];
                acc = fmaf(xv.x, wv.x, acc); acc = fmaf(xv.y, wv.y, acc);
                acc = fmaf(xv.z, wv.z, acc); acc = fmaf(xv.w, wv.w, acc);
            }
            acc += __shfl_xor(acc, 1);
            acc += __shfl_xor(acc, 2);
            acc += __shfl_xor(acc, 4);
            if (ks == 0) {
                float v = acc + dtbh;
                float sp = (v > 20.f) ? v : log1pf(expf(v));
                dtf[(size_t)(t0 + rw) * NH + h] = sp;
                dts[rw * NH + h] = sp;
            }
        }
    }
    // --- phase 2b: bf16 A-frags (own 2 from fp32 Xs, halo 1 from bf16 Hb) ---
    const int wm = wave >> 2, wn = wave & 3;
    const int fr = lane & 15, ko = lane >> 4;
    bf16x8 a0[4], a1[4], ah[4];
    #pragma unroll
    for (int kk = 0; kk < 4; kk++) {
        const float* s0 = &Xs[(wm * 32 + fr) * 132 + kk * 32 + ko * 8];
        const float* s1 = &Xs[(wm * 32 + 16 + fr) * 132 + kk * 32 + ko * 8];
        bf16x8 f0, f1;
        #pragma unroll
        for (int j = 0; j < 8; j++) { f0[j] = (bf16)s0[j]; f1[j] = (bf16)s1[j]; }
        a0[kk] = f0; a1[kk] = f1;
        ah[kk] = *(const bf16x8*)&Hb[fr * 136 + kk * 32 + ko * 8];
    }
    __syncthreads();                 // Xs/Hb/Wd dead -> XT may be written
    // --- phase 3 GEMM: 10 n-frags per wave; z -> global, xBC -> XT (ch-major) --
    for (int i = 0; i < 10; i++) {
        int f = i * 4 + wn;
        const unsigned short* wb = w1g + (((size_t)f * 4) << 9) + lane * 8;
        f32x4 acc0 = {}, acc1 = {}, accH = {};
        #pragma unroll
        for (int kk = 0; kk < 4; kk++) {
            bf16x8 bfr = *(const bf16x8*)(wb + ((size_t)kk << 9));
            acc0 = __builtin_amdgcn_mfma_f32_16x16x32_bf16(a0[kk], bfr, acc0, 0, 0, 0);
            acc1 = __builtin_amdgcn_mfma_f32_16x16x32_bf16(a1[kk], bfr, acc1, 0, 0, 0);
            if (i >= 4 && wm == 0)
                accH = __builtin_amdgcn_mfma_f32_16x16x32_bf16(ah[kk], bfr, accH, 0, 0, 0);
        }
        if (i < 4) {                     // z frag -> global
            int n = f * 16 + fr;
            #pragma unroll
            for (int rr = 0; rr < 4; rr++) {
                zb[(size_t)(t0 + wm * 32 + ko * 4 + rr) * DI + n]      = f2bfbits(acc0[rr]);
                zb[(size_t)(t0 + wm * 32 + 16 + ko * 4 + rr) * DI + n] = f2bfbits(acc1[rr]);
            }
        } else {                         // xBC frag -> XT channel-major, 8B stores
            int cc = f * 16 + fr - 256;
            bf16x4 p0, p1;
            #pragma unroll
            for (int rr = 0; rr < 4; rr++) { p0[rr] = (bf16)acc0[rr]; p1[rr] = (bf16)acc1[rr]; }
            *(bf16x4*)&XT[cc * 80 + 8 + wm * 32 + ko * 4]      = p0;
            *(bf16x4*)&XT[cc * 80 + 8 + wm * 32 + 16 + ko * 4] = p1;
            if (wm == 0 && ko == 3) {    // halo tokens t0-4..t0-1 -> cols 4..7
                bf16x4 pH;
                #pragma unroll
                for (int rr = 0; rr < 4; rr++) pH[rr] = (bf16)accH[rr];
                *(bf16x4*)&XT[cc * 80 + 4] = pH;
            }
        }
    }
    __syncthreads();
    // --- phase 4: conv K=4 + SiLU, register-resident row per channel ---
    if (tid < CDIM) {
        const int ch = tid;
        float4 wv = *(const float4*)(cw + ch * 4);
        float bias = cb[ch];
        bf16x4 hv = *(const bf16x4*)&XT[ch * 80 + 4];
        float h1 = 0.f, h2 = 0.f, h3 = 0.f;
        if (l0) { h1 = (float)hv[3]; h2 = (float)hv[2]; h3 = (float)hv[1]; }
        #pragma unroll
        for (int u = 0; u < 8; u++) {
            bf16x8 iv = *(const bf16x8*)&XT[ch * 80 + 8 + u * 8];
            bf16x8 ov;
            #pragma unroll
            for (int j = 0; j < 8; j++) {
                float x0 = (float)iv[j];
                float acc = bias;
                acc = fmaf(x0, wv.w, acc);
                acc = fmaf(h1, wv.z, acc);
                acc = fmaf(h2, wv.y, acc);
                acc = fmaf(h3, wv.x, acc);
                float s = acc / (1.f + expf(-acc));
                ov[j] = (bf16)s;
                if (ch >= 256) bcA[(size_t)(t0 + u * 8 + j) * 128 + (ch - 256)] = f2bfbits(s);
                h3 = h2; h2 = h1; h1 = x0;
            }
            *(bf16x8*)&XT[ch * 80 + 8 + u * 8] = ov;
        }
    }
    __syncthreads();
    // --- phase 5: xT writeout (coalesced b128) ---
    {
        int idx = tid;
        #pragma unroll
        for (int it = 0; it < 4; it++, idx += 512) {
            int row = idx >> 3, tc = (idx & 7) * 8;
            *(short8*)(xTg + (size_t)row * NTOK + t0 + tc) = *(const short8*)&XT[row * 80 + 8 + tc];
        }
    }
    // --- phase 6: ssd1, wave = head ---
    {
        const int h = wave;
        const int b = blockIdx.x >> 6, c = blockIdx.x & 63;
        const int bh = b * NH + h;
        const float A = -expf(alog[h]);
        float dt = dts[lane * NH + h];
        float q = dt * A * LOG2E;
        #pragma unroll
        for (int o = 1; o <= 32; o <<= 1) {
            float tmp = __shfl_up(q, o);
            if (lane >= o) q += tmp;
        }
        float qL = __shfl(q, 63);
        wlh[h * 64 + lane] = exp2f(qL - q) * dt;   // intra-wave LDS: no barrier
        if (lane == 0) dAp[(size_t)bh * NC + c] = exp2f(qL);
        const int m = lane & 15;
        f32x4 hacc[4][2] = {};
        #pragma unroll
        for (int kh = 0; kh < 2; kh++) {
            bf16x8 xb[2];
            #pragma unroll
            for (int pi = 0; pi < 2; pi++)
                xb[pi] = *(const bf16x8*)&XT[(h * HD + pi * 16 + m) * 80 + 8 + kh * 32 + ko * 8];
            f32x4 w0 = *(const f32x4*)&wlh[h * 64 + kh * 32 + ko * 8];
            f32x4 w1v = *(const f32x4*)&wlh[h * 64 + kh * 32 + ko * 8 + 4];
            #pragma unroll
            for (int ni = 0; ni < 4; ni++) {
                bf16x8 bv = *(const bf16x8*)&XT[(256 + ni * 16 + m) * 80 + 8 + kh * 32 + ko * 8];
                bf16x8 af;
                #pragma unroll
                for (int j = 0; j < 4; j++) af[j] = (bf16)((float)bv[j] * w0[j]);
                #pragma unroll
                for (int j = 0; j < 4; j++) af[4 + j] = (bf16)((float)bv[4 + j] * w1v[j]);
                #pragma unroll
                for (int pi = 0; pi < 2; pi++)
                    hacc[ni][pi] = __builtin_amdgcn_mfma_f32_16x16x32_bf16(af, xb[pi], hacc[ni][pi], 0, 0, 0);
            }
        }
        unsigned short* hb = hst + (((size_t)bh * NC + c) << 11);
        #pragma unroll
        for (int ni = 0; ni < 4; ni++)
            #pragma unroll
            for (int pi = 0; pi < 2; pi++) {
                bf16x4 pv;
                #pragma unroll
                for (int r = 0; r < 4; r++) pv[r] = (bf16)hacc[ni][pi][r];
                *(bf16x4*)(hb + (pi * 16 + m) * 64 + ni * 16 + ko * 4) = pv;
            }
    }
}

// ---------------- 5b. SSM pass 2: scan, 1 bh/block, depth-4 load pipeline ------
__global__ __launch_bounds__(256) void k_ssm2(unsigned short* __restrict__ hst,
                                              const float* __restrict__ dAp) {
    __shared__ float dl[NC];
    const int bh = blockIdx.x >> 3, seg = blockIdx.x & 7;
    const int s = seg * 256 + threadIdx.x;
    if (threadIdx.x < NC) dl[threadIdx.x] = dAp[(size_t)bh * NC + threadIdx.x];
    __syncthreads();
    unsigned short* p = hst + ((size_t)bh * NC << 11) + s;
    float r = 0.f;
    float v0 = bfbits2f(p[0]);
    float v1 = bfbits2f(p[(size_t)1 << 11]);
    float v2 = bfbits2f(p[(size_t)2 << 11]);
    float v3 = bfbits2f(p[(size_t)3 << 11]);
    for (int c = 0; c < NC; c += 4) {
        float t;
        t = v0; if (c + 4 < NC) v0 = bfbits2f(p[(size_t)(c + 4) << 11]);
        p[(size_t)c << 11] = f2bfbits(r);       r = fmaf(r, dl[c], t);
        t = v1; if (c + 5 < NC) v1 = bfbits2f(p[(size_t)(c + 5) << 11]);
        p[(size_t)(c + 1) << 11] = f2bfbits(r); r = fmaf(r, dl[c + 1], t);
        t = v2; if (c + 6 < NC) v2 = bfbits2f(p[(size_t)(c + 6) << 11]);
        p[(size_t)(c + 2) << 11] = f2bfbits(r); r = fmaf(r, dl[c + 2], t);
        t = v3; if (c + 7 < NC) v3 = bfbits2f(p[(size_t)(c + 7) << 11]);
        p[(size_t)(c + 3) << 11] = f2bfbits(r); r = fmaf(r, dl[c + 3], t);
    }
}

// ---------------- 5c+6+7. fused SSD pass 3 + gate + GEMM2 + residual -----------
__global__ __launch_bounds__(512, 2) void k_ssd3g(const unsigned short* __restrict__ bcA,
                                                  const unsigned short* __restrict__ xT,
                                                  const float* __restrict__ dtf,
                                                  const float* __restrict__ alog,
                                                  const unsigned short* __restrict__ hst,
                                                  const float* __restrict__ Dw,
                                                  const unsigned short* __restrict__ zb,
                                                  const unsigned short* __restrict__ w2f,
                                                  const float* __restrict__ xin,
                                                  float* __restrict__ out) {
    __shared__ __align__(16) unsigned short BC[64][136];   // B|C chunk, all heads
    __shared__ __align__(16) bf16 PlY[NH][64 * 40];        // per-wave P half; alias: Ys[64][264]
    __shared__ float ql[NH][64];
    __shared__ float dl[NH][64];
    const int tid = threadIdx.x;
    const int b = blockIdx.x >> 6, c = blockIdx.x & 63;
    const int t0 = blockIdx.x * 64;
    const size_t tok0 = (size_t)t0;
    {
        int idx = tid;
        #pragma unroll
        for (int it = 0; it < 2; it++, idx += 512) {
            int tok = idx >> 4, c8 = (idx & 15) * 8;
            *(short8*)&BC[tok][c8] = *(const short8*)(bcA + (tok0 + tok) * 128 + c8);
        }
    }
    __syncthreads();
    const int h = tid >> 6, lane = tid & 63;
    const int bh = b * NH + h;
    const float A = -expf(alog[h]);
    const float Dh = Dw[h];
    float dt = dtf[(tok0 + lane) * NH + h];
    float q = dt * A * LOG2E;
    #pragma unroll
    for (int o = 1; o <= 32; o <<= 1) {
        float tmp = __shfl_up(q, o);
        if (lane >= o) q += tmp;
    }
    ql[h][lane] = q;                           // intra-wave LDS, no barrier
    dl[h][lane] = dt;
    const int m = lane & 15, ko = lane >> 4;
    bf16* Pw = &PlY[h][0];
    bf16x8 cf[4][2];
    #pragma unroll
    for (int ti = 0; ti < 4; ti++)
        #pragma unroll
        for (int kh = 0; kh < 2; kh++)
            cf[ti][kh] = *(const bf16x8*)&BC[ti * 16 + m][64 + kh * 32 + ko * 8];
    float qt[4];
    #pragma unroll
    for (int ti = 0; ti < 4; ti++) qt[ti] = ql[h][ti * 16 + m];
    const size_t hbase = ((size_t)bh * NC + c) << 11;
    f32x4 ya[4][2] = {}, ua[4][2] = {};
    #pragma unroll
    for (int kh = 0; kh < 2; kh++) {
        bf16x8 hb2[2];
        #pragma unroll
        for (int pi = 0; pi < 2; pi++)
            hb2[pi] = *(const bf16x8*)(hst + hbase + (pi * 16 + m) * 64 + kh * 32 + ko * 8);
        #pragma unroll
        for (int ti = 0; ti < 4; ti++)
            #pragma unroll
            for (int pi = 0; pi < 2; pi++)
                ua[ti][pi] = __builtin_amdgcn_mfma_f32_16x16x32_bf16(cf[ti][kh], hb2[pi], ua[ti][pi], 0, 0, 0);
    }
    #pragma unroll
    for (int sh = 0; sh < 2; sh++) {
        f32x4 gth[4][2] = {};
        #pragma unroll
        for (int kh = 0; kh < 2; kh++) {
            bf16x8 bfg[2];
            #pragma unroll
            for (int sj = 0; sj < 2; sj++)
                bfg[sj] = *(const bf16x8*)&BC[(sh * 2 + sj) * 16 + m][kh * 32 + ko * 8];
            #pragma unroll
            for (int ti = 0; ti < 4; ti++)
                #pragma unroll
                for (int sj = 0; sj < 2; sj++)
                    gth[ti][sj] = __builtin_amdgcn_mfma_f32_16x16x32_bf16(bfg[sj], cf[ti][kh], gth[ti][sj], 0, 0, 0);
        }
        #pragma unroll
        for (int sj = 0; sj < 2; sj++) {
            const int si = sh * 2 + sj;
            f32x4 qs = *(const f32x4*)&ql[h][si * 16 + ko * 4];
            f32x4 ds = *(const f32x4*)&dl[h][si * 16 + ko * 4];
            #pragma unroll
            for (int ti = 0; ti < 4; ti++) {
                bf16x4 pv = {};
                if (si <= ti) {
                    const int t = ti * 16 + m;
                    #pragma unroll
                    for (int r = 0; r < 4; r++) {
                        int s = si * 16 + ko * 4 + r;
                        float p = 0.f;
                        if (s <= t) {
                            p = exp2f(qt[ti] - qs[r]) * ds[r] * gth[ti][sj][r];
                            if (s == t) p += Dh;
                        }
                        pv[r] = (bf16)p;
                    }
                }
                *(bf16x4*)&Pw[(ti * 16 + m) * 40 + sj * 16 + ko * 4] = pv;
            }
        }
        bf16x8 xb[2];
        #pragma unroll
        for (int pi = 0; pi < 2; pi++)
            xb[pi] = *(const bf16x8*)(xT + (size_t)(h * HD + pi * 16 + m) * NTOK + tok0 + sh * 32 + ko * 8);
        #pragma unroll
        for (int ti = 0; ti < 4; ti++) {
            bf16x8 pa = *(const bf16x8*)&Pw[(ti * 16 + m) * 40 + ko * 8];
            #pragma unroll
            for (int pi = 0; pi < 2; pi++)
                ya[ti][pi] = __builtin_amdgcn_mfma_f32_16x16x32_bf16(pa, xb[pi], ya[ti][pi], 0, 0, 0);
        }
    }
    __syncthreads();
    unsigned short* Ys = (unsigned short*)&PlY[0][0];    // [64][264]
    {
        f32x4 et[4];
        #pragma unroll
        for (int ti = 0; ti < 4; ti++) {
            f32x4 qv = *(const f32x4*)&ql[h][ti * 16 + ko * 4];
            #pragma unroll
            for (int r = 0; r < 4; r++) et[ti][r] = exp2f(qv[r]);
        }
        #pragma unroll
        for (int ti = 0; ti < 4; ti++)
            #pragma unroll
            for (int pi = 0; pi < 2; pi++)
                #pragma unroll
                for (int r = 0; r < 4; r++) {
                    int t = ti * 16 + ko * 4 + r;
                    Ys[t * 264 + h * HD + pi * 16 + m] =
                        f2bfbits(ya[ti][pi][r] + et[ti][r] * ua[ti][pi][r]);
                }
    }
    __syncthreads();
    {
        const int rg = h & 3, nh = h >> 2;
        const int r0 = rg * 16;
        const size_t rowo = (tok0 + r0 + m) * DI;
        float ss = 0.f;
        bf16x8 gb[8];
        #pragma unroll
        for (int kk = 0; kk < 8; kk++) {
            int co = kk * 32 + ko * 8;
            bf16x8 yv = *(const bf16x8*)&Ys[(r0 + m) * 264 + co];
            bf16x8 zv = *(const bf16x8*)(zb + rowo + co);
            #pragma unroll
            for (int j = 0; j < 8; j++) {
                float z = (float)zv[j];
                float g = (float)yv[j] * (z / (1.f + expf(-z)));
                ss += g * g;
                gb[kk][j] = (bf16)g;
            }
        }
        ss += __shfl_xor(ss, 16);
        ss += __shfl_xor(ss, 32);
        const float rs = rsqrtf(ss * (1.0f / DI) + EPSF);
        #pragma unroll
        for (int kk = 0; kk < 8; kk++)
            #pragma unroll
            for (int j = 0; j < 8; j++)
                gb[kk][j] = (bf16)((float)gb[kk][j] * rs);
        const unsigned short* wp = w2f + (size_t)lane * 8;
        f32x4 acc[4] = {};
        #pragma unroll
        for (int kk = 0; kk < 8; kk++) {
            #pragma unroll
            for (int ntl = 0; ntl < 4; ntl++) {
                bf16x8 bfr = *(const bf16x8*)(wp + (((size_t)kk * 8 + nh * 4 + ntl) << 9));
                acc[ntl] = __builtin_amdgcn_mfma_f32_16x16x32_bf16(gb[kk], bfr, acc[ntl], 0, 0, 0);
            }
        }
        #pragma unroll
        for (int ntl = 0; ntl < 4; ntl++) {
            int n = (nh * 4 + ntl) * 16 + m;
            #pragma unroll
            for (int rr = 0; rr < 4; rr++) {
                size_t row = tok0 + r0 + ko * 4 + rr;
                out[row * DM + n] = xin[row * DM + n] + acc[ntl][rr];
            }
        }
    }
}

extern "C" void kernel_launch(void* const* d_in, const int* in_sizes, int n_in,
                              void* d_out, int out_size, void* d_ws, size_t ws_size,
                              hipStream_t stream) {
    const float* x   = (const float*)d_in[0];
    const float* nw  = (const float*)d_in[1];
    const float* w1  = (const float*)d_in[2];
    const float* cw  = (const float*)d_in[3];
    const float* cb  = (const float*)d_in[4];
    const float* dtb = (const float*)d_in[5];
    const float* al  = (const float*)d_in[6];
    const float* Dw  = (const float*)d_in[7];
    const float* gw  = (const float*)d_in[8];
    const float* w2  = (const float*)d_in[9];
    float* out = (float*)d_out;

    float* ws = (float*)d_ws;
    float*  dAp = ws;                                   // 4096 fp32
    float*  dtf = dAp + NB * NH * NC;                   // NTOK*8 fp32
    unsigned short* hst = (unsigned short*)(dtf + (size_t)NTOK * NH); // 64*64*2048 bf16
    unsigned short* zb  = hst + (size_t)NB * NH * NC * 2048;          // NTOK*256
    unsigned short* bcA = zb + (size_t)NTOK * DI;                     // NTOK*128 (B|C tok-major)
    unsigned short* xT  = bcA + (size_t)NTOK * 128;                   // 256*NTOK (x ch-major)
    unsigned short* w1g = xT + (size_t)DI * NTOK;                     // 640*128 frag-packed
    unsigned short* w2f = w1g + (size_t)640 * DM;                     // 128*256 frag-packed

    k_prep<<<(640 * DM + DM * DI + 255) / 256, 256, 0, stream>>>(w1, w2, gw, w1g, w2f);
    k_front<<<NTOK / 64, 512, 0, stream>>>(x, nw, w1, dtb, w1g, cw, cb, al,
                                           zb, dtf, bcA, xT, hst, dAp);
    k_ssm2<<<NB * NH * 8, 256, 0, stream>>>(hst, dAp);
    k_ssd3g<<<NTOK / 64, 512, 0, stream>>>(bcA, xT, dtf, al, hst, Dw, zb, w2f, x, out);
}

// Round 10
// 163.282 us; speedup vs baseline: 1.1033x; 1.0118x over previous
//
#include <hip/hip_runtime.h>

#define DM    128
#define DI    256
#define NH    8
#define HD    32
#define NS    64
#define CDIM  384
#define DPROJ 648
#define LSEQ  4096
#define NB    8
#define NTOK  32768          // NB*LSEQ
#define LC    64             // chunk length
#define NC    64             // chunks per (b,h) sequence
#define EPSF  1e-5f
#define LOG2E 1.4426950408889634f

typedef __bf16 bf16;
typedef bf16  bf16x8 __attribute__((ext_vector_type(8)));
typedef bf16  bf16x4 __attribute__((ext_vector_type(4)));
typedef short short8 __attribute__((ext_vector_type(8)));
typedef float f32x4  __attribute__((ext_vector_type(4)));

__device__ __forceinline__ unsigned short f2bfbits(float f) {
    unsigned int u = __float_as_uint(f);
    unsigned int r = u + 0x7FFFu + ((u >> 16) & 1u);   // RNE
    return (unsigned short)(r >> 16);
}
__device__ __forceinline__ float bfbits2f(unsigned short u) {
    return __uint_as_float(((unsigned int)u) << 16);
}

// ---------------- 0. prep: W1 + W2 fragment-packs (gnorm folded into W2) -------
__global__ __launch_bounds__(256) void k_prep(const float* __restrict__ w1,
                                              const float* __restrict__ w2,
                                              const float* __restrict__ gw,
                                              unsigned short* __restrict__ w1g,
                                              unsigned short* __restrict__ w2f) {
    int i = blockIdx.x * 256 + threadIdx.x;
    if (i < 640 * DM) {
        int f = i >> 9, r = i & 511;
        int lane = r >> 3, jj = r & 7;
        int ns = f >> 2, kk = f & 3;
        int n = ns * 16 + (lane & 15), k = kk * 32 + (lane >> 4) * 8 + jj;
        w1g[i] = f2bfbits(w1[(size_t)n * DM + k]);
    } else {
        int j = i - 640 * DM;
        if (j < DM * DI) {
            int f = j >> 9, r = j & 511;
            int lane = r >> 3, jj = r & 7;
            int kk = f >> 3, nt = f & 7;
            int fr = lane & 15, ko = lane >> 4;
            int n = nt * 16 + fr, k = kk * 32 + ko * 8 + jj;
            w2f[j] = f2bfbits(w2[(size_t)n * DI + k] * gw[k]);
        }
    }
}

// ---------------- FRONT: rmsnorm + dt + GEMM1 + conv + ssd1, 64KB LDS ----------
// LDS (identical to the R7-proven layout, NO swizzle):
//   [0     ..33792)  Xs [64][132] f32  ALIAS (phase 3+) XT [384][80] bf16
//        XT row = channel; col 4..7 = halo tokens t0-4..t0-1; own at col 8..71
//   [33792 ..38144)  Hb  [16][136] bf16   (halo rmsnorm rows; dead after ph2)
//   [38144 ..42368)  Wd  [8][132]  f32    (dt weight rows; dead after ph2)
//   [61440 ..63488)  dts [64][8]   f32    (persistent)
//   [63488 ..65536)  wlh [8][64]   f32    (persistent)
// Conv (only change vs R7): 384ch x 4 sixteen-token quarters = 1536 tasks over
// 512 threads (3 each); inputs+history register-staged before a barrier
// (WAR-safe), then 3 independent 16-step chains; in-place writeback.
__global__ __launch_bounds__(512, 4) void k_front(const float* __restrict__ x,
                                                  const float* __restrict__ nw,
                                                  const float* __restrict__ w1,
                                                  const float* __restrict__ dtb,
                                                  const unsigned short* __restrict__ w1g,
                                                  const float* __restrict__ cw,
                                                  const float* __restrict__ cb,
                                                  const float* __restrict__ alog,
                                                  unsigned short* __restrict__ zb,
                                                  float* __restrict__ dtf,
                                                  unsigned short* __restrict__ bcA,
                                                  unsigned short* __restrict__ xTg,
                                                  unsigned short* __restrict__ hst,
                                                  float* __restrict__ dAp) {
    __shared__ __align__(16) unsigned char SMEM[65536];
    float*          Xs  = (float*)SMEM;                    // [64][132]
    unsigned short* XT  = (unsigned short*)SMEM;           // [384][80] (alias)
    unsigned short* Hb  = (unsigned short*)(SMEM + 33792); // [16][136]
    float*          Wd  = (float*)(SMEM + 38144);          // [8][132]
    float*          dts = (float*)(SMEM + 61440);          // [64][8]
    float*          wlh = (float*)(SMEM + 63488);          // [8][64]
    const int tid = threadIdx.x;
    const int wave = tid >> 6, lane = tid & 63;
    const int t0 = blockIdx.x * 64;
    const int l0 = t0 & (LSEQ - 1);
    // stage dt weight rows (fp32)
    if (tid < 256) {
        int row = tid >> 5, col = (tid & 31) * 4;
        *(float4*)&Wd[row * 132 + col] = *(const float4*)(w1 + (size_t)(640 + row) * DM + col);
    }
    // --- phase 1: rmsnorm 80 rows; halo -> bf16 Hb, own -> fp32 Xs ---
    const float nw0 = nw[lane * 2], nw1 = nw[lane * 2 + 1];
    #pragma unroll
    for (int i = 0; i < 10; i++) {
        int r = wave * 10 + i;
        int tok = t0 + r - 16; if (tok < 0) tok = 0;    // clamp (unused when l0==0)
        const float* xr = x + (size_t)tok * DM + lane * 2;
        float v0 = xr[0], v1 = xr[1];
        float ss = v0 * v0 + v1 * v1;
        #pragma unroll
        for (int o = 32; o; o >>= 1) ss += __shfl_xor(ss, o);
        float rs = rsqrtf(ss * (1.0f / DM) + EPSF);
        float o0 = v0 * rs * nw0, o1 = v1 * rs * nw1;
        if (r < 16) {
            ushort2 hb; hb.x = f2bfbits(o0); hb.y = f2bfbits(o1);
            *(ushort2*)&Hb[r * 136 + lane * 2] = hb;
        } else {
            Xs[(r - 16) * 132 + lane * 2]     = o0;
            Xs[(r - 16) * 132 + lane * 2 + 1] = o1;
        }
    }
    __syncthreads();
    // --- phase 2a: dt (fp32 exact), 8 own rows per wave ---
    {
        const int h = lane >> 3, ks = lane & 7;
        const float dtbh = dtb[h];
        #pragma unroll
        for (int i = 0; i < 8; i++) {
            int rw = wave * 8 + i;
            float acc = 0.f;
            #pragma unroll
            for (int q = 0; q < 4; q++) {
                float4 xv = *(const float4*)&Xs[rw * 132 + ks * 16 + q * 4];
                float4 wv = *(const float4*)&Wd[h * 132 + ks * 16 + q * 4];
                acc = fmaf(xv.x, wv.x, acc); acc = fmaf(xv.y, wv.y, acc);
                acc = fmaf(xv.z, wv.z, acc); acc = fmaf(xv.w, wv.w, acc);
            }
            acc += __shfl_xor(acc, 1);
            acc += __shfl_xor(acc, 2);
            acc += __shfl_xor(acc, 4);
            if (ks == 0) {
                float v = acc + dtbh;
                float sp = (v > 20.f) ? v : log1pf(expf(v));
                dtf[(size_t)(t0 + rw) * NH + h] = sp;
                dts[rw * NH + h] = sp;
            }
        }
    }
    // --- phase 2b: bf16 A-frags (own 2 from fp32 Xs, halo 1 from bf16 Hb) ---
    const int wm = wave >> 2, wn = wave & 3;
    const int fr = lane & 15, ko = lane >> 4;
    bf16x8 a0[4], a1[4], ah[4];
    #pragma unroll
    for (int kk = 0; kk < 4; kk++) {
        const float* s0 = &Xs[(wm * 32 + fr) * 132 + kk * 32 + ko * 8];
        const float* s1 = &Xs[(wm * 32 + 16 + fr) * 132 + kk * 32 + ko * 8];
        bf16x8 f0, f1;
        #pragma unroll
        for (int j = 0; j < 8; j++) { f0[j] = (bf16)s0[j]; f1[j] = (bf16)s1[j]; }
        a0[kk] = f0; a1[kk] = f1;
        ah[kk] = *(const bf16x8*)&Hb[fr * 136 + kk * 32 + ko * 8];
    }
    __syncthreads();                 // Xs/Hb/Wd dead -> XT may be written
    // --- phase 3 GEMM: z -> global, xBC -> XT (ch-major, linear units) ---
    for (int i = 0; i < 10; i++) {
        int f = i * 4 + wn;
        const unsigned short* wb = w1g + (((size_t)f * 4) << 9) + lane * 8;
        f32x4 acc0 = {}, acc1 = {}, accH = {};
        #pragma unroll
        for (int kk = 0; kk < 4; kk++) {
            bf16x8 bfr = *(const bf16x8*)(wb + ((size_t)kk << 9));
            acc0 = __builtin_amdgcn_mfma_f32_16x16x32_bf16(a0[kk], bfr, acc0, 0, 0, 0);
            acc1 = __builtin_amdgcn_mfma_f32_16x16x32_bf16(a1[kk], bfr, acc1, 0, 0, 0);
            if (i >= 4 && wm == 0)
                accH = __builtin_amdgcn_mfma_f32_16x16x32_bf16(ah[kk], bfr, accH, 0, 0, 0);
        }
        if (i < 4) {                     // z frag -> global
            int n = f * 16 + fr;
            #pragma unroll
            for (int rr = 0; rr < 4; rr++) {
                zb[(size_t)(t0 + wm * 32 + ko * 4 + rr) * DI + n]      = f2bfbits(acc0[rr]);
                zb[(size_t)(t0 + wm * 32 + 16 + ko * 4 + rr) * DI + n] = f2bfbits(acc1[rr]);
            }
        } else {                         // xBC frag -> XT, 8B stores
            int cc = f * 16 + fr - 256;
            bf16x4 p0, p1;
            #pragma unroll
            for (int rr = 0; rr < 4; rr++) { p0[rr] = (bf16)acc0[rr]; p1[rr] = (bf16)acc1[rr]; }
            *(bf16x4*)&XT[cc * 80 + 8 + wm * 32 + ko * 4]      = p0;
            *(bf16x4*)&XT[cc * 80 + 8 + wm * 32 + 16 + ko * 4] = p1;
            if (wm == 0 && ko == 3) {    // halo tokens t0-4..t0-1 -> cols 4..7
                bf16x4 pH;
                #pragma unroll
                for (int rr = 0; rr < 4; rr++) pH[rr] = (bf16)accH[rr];
                *(bf16x4*)&XT[cc * 80 + 4] = pH;
            }
        }
    }
    __syncthreads();
    // --- phase 4a: conv input staging (registers; WAR-safe across barrier) ---
    int tch[3], tq[3];
    bf16x8 ci[3][2];
    bf16x4 chh[3];
    #pragma unroll
    for (int k = 0; k < 3; k++) {
        int task = tid + k * 512;
        int q = task / 384, ch = task - q * 384;
        tch[k] = ch; tq[k] = q;
        ci[k][0] = *(const bf16x8*)&XT[ch * 80 + 8 + q * 16];
        ci[k][1] = *(const bf16x8*)&XT[ch * 80 + 8 + q * 16 + 8];
        chh[k] = (q == 0)
            ? *(const bf16x4*)&XT[ch * 80 + 4]
            : *(const bf16x4*)&XT[ch * 80 + 8 + q * 16 - 4];
    }
    __syncthreads();
    // --- phase 4b: conv K=4 + SiLU compute + writeback (3 independent chains) --
    #pragma unroll
    for (int k = 0; k < 3; k++) {
        const int ch = tch[k], q = tq[k];
        float4 wv = *(const float4*)(cw + ch * 4);
        float bias = cb[ch];
        float h1 = (float)chh[k][3], h2 = (float)chh[k][2], h3 = (float)chh[k][1];
        if (q == 0 && !l0) { h1 = 0.f; h2 = 0.f; h3 = 0.f; }
        #pragma unroll
        for (int u = 0; u < 2; u++) {
            bf16x8 iv = ci[k][u];
            bf16x8 ov;
            #pragma unroll
            for (int j = 0; j < 8; j++) {
                float x0 = (float)iv[j];
                float acc = bias;
                acc = fmaf(x0, wv.w, acc);
                acc = fmaf(h1, wv.z, acc);
                acc = fmaf(h2, wv.y, acc);
                acc = fmaf(h3, wv.x, acc);
                float s = acc / (1.f + expf(-acc));
                ov[j] = (bf16)s;
                if (ch >= 256)
                    bcA[(size_t)(t0 + q * 16 + u * 8 + j) * 128 + (ch - 256)] = f2bfbits(s);
                h3 = h2; h2 = h1; h1 = x0;
            }
            *(bf16x8*)&XT[ch * 80 + 8 + q * 16 + u * 8] = ov;
        }
    }
    __syncthreads();
    // --- phase 5: xT writeout (coalesced b128) ---
    {
        int idx = tid;
        #pragma unroll
        for (int it = 0; it < 4; it++, idx += 512) {
            int row = idx >> 3, tc = (idx & 7) * 8;
            *(short8*)(xTg + (size_t)row * NTOK + t0 + tc) = *(const short8*)&XT[row * 80 + 8 + tc];
        }
    }
    // --- phase 6: ssd1, wave = head ---
    {
        const int h = wave;
        const int b = blockIdx.x >> 6, c = blockIdx.x & 63;
        const int bh = b * NH + h;
        const float A = -expf(alog[h]);
        float dt = dts[lane * NH + h];
        float q = dt * A * LOG2E;
        #pragma unroll
        for (int o = 1; o <= 32; o <<= 1) {
            float tmp = __shfl_up(q, o);
            if (lane >= o) q += tmp;
        }
        float qL = __shfl(q, 63);
        wlh[h * 64 + lane] = exp2f(qL - q) * dt;   // intra-wave LDS: no barrier
        if (lane == 0) dAp[(size_t)bh * NC + c] = exp2f(qL);
        const int m = lane & 15;
        f32x4 hacc[4][2] = {};
        #pragma unroll
        for (int kh = 0; kh < 2; kh++) {
            bf16x8 xb[2];
            #pragma unroll
            for (int pi = 0; pi < 2; pi++)
                xb[pi] = *(const bf16x8*)&XT[(h * HD + pi * 16 + m) * 80 + 8 + kh * 32 + ko * 8];
            f32x4 w0 = *(const f32x4*)&wlh[h * 64 + kh * 32 + ko * 8];
            f32x4 w1v = *(const f32x4*)&wlh[h * 64 + kh * 32 + ko * 8 + 4];
            #pragma unroll
            for (int ni = 0; ni < 4; ni++) {
                bf16x8 bv = *(const bf16x8*)&XT[(256 + ni * 16 + m) * 80 + 8 + kh * 32 + ko * 8];
                bf16x8 af;
                #pragma unroll
                for (int j = 0; j < 4; j++) af[j] = (bf16)((float)bv[j] * w0[j]);
                #pragma unroll
                for (int j = 0; j < 4; j++) af[4 + j] = (bf16)((float)bv[4 + j] * w1v[j]);
                #pragma unroll
                for (int pi = 0; pi < 2; pi++)
                    hacc[ni][pi] = __builtin_amdgcn_mfma_f32_16x16x32_bf16(af, xb[pi], hacc[ni][pi], 0, 0, 0);
            }
        }
        unsigned short* hb = hst + (((size_t)bh * NC + c) << 11);
        #pragma unroll
        for (int ni = 0; ni < 4; ni++)
            #pragma unroll
            for (int pi = 0; pi < 2; pi++) {
                bf16x4 pv;
                #pragma unroll
                for (int r = 0; r < 4; r++) pv[r] = (bf16)hacc[ni][pi][r];
                *(bf16x4*)(hb + (pi * 16 + m) * 64 + ni * 16 + ko * 4) = pv;
            }
    }
}

// ---------------- 5b. SSM pass 2: scan, 1 bh/block, depth-4 load pipeline ------
__global__ __launch_bounds__(256) void k_ssm2(unsigned short* __restrict__ hst,
                                              const float* __restrict__ dAp) {
    __shared__ float dl[NC];
    const int bh = blockIdx.x >> 3, seg = blockIdx.x & 7;
    const int s = seg * 256 + threadIdx.x;
    if (threadIdx.x < NC) dl[threadIdx.x] = dAp[(size_t)bh * NC + threadIdx.x];
    __syncthreads();
    unsigned short* p = hst + ((size_t)bh * NC << 11) + s;
    float r = 0.f;
    float v0 = bfbits2f(p[0]);
    float v1 = bfbits2f(p[(size_t)1 << 11]);
    float v2 = bfbits2f(p[(size_t)2 << 11]);
    float v3 = bfbits2f(p[(size_t)3 << 11]);
    for (int c = 0; c < NC; c += 4) {
        float t;
        t = v0; if (c + 4 < NC) v0 = bfbits2f(p[(size_t)(c + 4) << 11]);
        p[(size_t)c << 11] = f2bfbits(r);       r = fmaf(r, dl[c], t);
        t = v1; if (c + 5 < NC) v1 = bfbits2f(p[(size_t)(c + 5) << 11]);
        p[(size_t)(c + 1) << 11] = f2bfbits(r); r = fmaf(r, dl[c + 1], t);
        t = v2; if (c + 6 < NC) v2 = bfbits2f(p[(size_t)(c + 6) << 11]);
        p[(size_t)(c + 2) << 11] = f2bfbits(r); r = fmaf(r, dl[c + 2], t);
        t = v3; if (c + 7 < NC) v3 = bfbits2f(p[(size_t)(c + 7) << 11]);
        p[(size_t)(c + 3) << 11] = f2bfbits(r); r = fmaf(r, dl[c + 3], t);
    }
}

// ---------------- 5c+6+7. fused SSD pass 3 + gate + GEMM2 + residual -----------
__global__ __launch_bounds__(512, 2) void k_ssd3g(const unsigned short* __restrict__ bcA,
                                                  const unsigned short* __restrict__ xT,
                                                  const float* __restrict__ dtf,
                                                  const float* __restrict__ alog,
                                                  const unsigned short* __restrict__ hst,
                                                  const float* __restrict__ Dw,
                                                  const unsigned short* __restrict__ zb,
                                                  const unsigned short* __restrict__ w2f,
                                                  const float* __restrict__ xin,
                                                  float* __restrict__ out) {
    __shared__ __align__(16) unsigned short BC[64][136];   // B|C chunk, all heads
    __shared__ __align__(16) bf16 PlY[NH][64 * 40];        // per-wave P half; alias: Ys[64][264]
    __shared__ float ql[NH][64];
    __shared__ float dl[NH][64];
    const int tid = threadIdx.x;
    const int b = blockIdx.x >> 6, c = blockIdx.x & 63;
    const int t0 = blockIdx.x * 64;
    const size_t tok0 = (size_t)t0;
    {
        int idx = tid;
        #pragma unroll
        for (int it = 0; it < 2; it++, idx += 512) {
            int tok = idx >> 4, c8 = (idx & 15) * 8;
            *(short8*)&BC[tok][c8] = *(const short8*)(bcA + (tok0 + tok) * 128 + c8);
        }
    }
    __syncthreads();
    const int h = tid >> 6, lane = tid & 63;
    const int bh = b * NH + h;
    const float A = -expf(alog[h]);
    const float Dh = Dw[h];
    float dt = dtf[(tok0 + lane) * NH + h];
    float q = dt * A * LOG2E;
    #pragma unroll
    for (int o = 1; o <= 32; o <<= 1) {
        float tmp = __shfl_up(q, o);
        if (lane >= o) q += tmp;
    }
    ql[h][lane] = q;                           // intra-wave LDS, no barrier
    dl[h][lane] = dt;
    const int m = lane & 15, ko = lane >> 4;
    bf16* Pw = &PlY[h][0];
    bf16x8 cf[4][2];
    #pragma unroll
    for (int ti = 0; ti < 4; ti++)
        #pragma unroll
        for (int kh = 0; kh < 2; kh++)
            cf[ti][kh] = *(const bf16x8*)&BC[ti * 16 + m][64 + kh * 32 + ko * 8];
    float qt[4];
    #pragma unroll
    for (int ti = 0; ti < 4; ti++) qt[ti] = ql[h][ti * 16 + m];
    const size_t hbase = ((size_t)bh * NC + c) << 11;
    f32x4 ya[4][2] = {}, ua[4][2] = {};
    #pragma unroll
    for (int kh = 0; kh < 2; kh++) {
        bf16x8 hb2[2];
        #pragma unroll
        for (int pi = 0; pi < 2; pi++)
            hb2[pi] = *(const bf16x8*)(hst + hbase + (pi * 16 + m) * 64 + kh * 32 + ko * 8);
        #pragma unroll
        for (int ti = 0; ti < 4; ti++)
            #pragma unroll
            for (int pi = 0; pi < 2; pi++)
                ua[ti][pi] = __builtin_amdgcn_mfma_f32_16x16x32_bf16(cf[ti][kh], hb2[pi], ua[ti][pi], 0, 0, 0);
    }
    #pragma unroll
    for (int sh = 0; sh < 2; sh++) {
        f32x4 gth[4][2] = {};
        #pragma unroll
        for (int kh = 0; kh < 2; kh++) {
            bf16x8 bfg[2];
            #pragma unroll
            for (int sj = 0; sj < 2; sj++)
                bfg[sj] = *(const bf16x8*)&BC[(sh * 2 + sj) * 16 + m][kh * 32 + ko * 8];
            #pragma unroll
            for (int ti = 0; ti < 4; ti++)
                #pragma unroll
                for (int sj = 0; sj < 2; sj++)
                    gth[ti][sj] = __builtin_amdgcn_mfma_f32_16x16x32_bf16(bfg[sj], cf[ti][kh], gth[ti][sj], 0, 0, 0);
        }
        #pragma unroll
        for (int sj = 0; sj < 2; sj++) {
            const int si = sh * 2 + sj;
            f32x4 qs = *(const f32x4*)&ql[h][si * 16 + ko * 4];
            f32x4 ds = *(const f32x4*)&dl[h][si * 16 + ko * 4];
            #pragma unroll
            for (int ti = 0; ti < 4; ti++) {
                bf16x4 pv = {};
                if (si <= ti) {
                    const int t = ti * 16 + m;
                    #pragma unroll
                    for (int r = 0; r < 4; r++) {
                        int s = si * 16 + ko * 4 + r;
                        float p = 0.f;
                        if (s <= t) {
                            p = exp2f(qt[ti] - qs[r]) * ds[r] * gth[ti][sj][r];
                            if (s == t) p += Dh;
                        }
                        pv[r] = (bf16)p;
                    }
                }
                *(bf16x4*)&Pw[(ti * 16 + m) * 40 + sj * 16 + ko * 4] = pv;
            }
        }
        bf16x8 xb[2];
        #pragma unroll
        for (int pi = 0; pi < 2; pi++)
            xb[pi] = *(const bf16x8*)(xT + (size_t)(h * HD + pi * 16 + m) * NTOK + tok0 + sh * 32 + ko * 8);
        #pragma unroll
        for (int ti = 0; ti < 4; ti++) {
            bf16x8 pa = *(const bf16x8*)&Pw[(ti * 16 + m) * 40 + ko * 8];
            #pragma unroll
            for (int pi = 0; pi < 2; pi++)
                ya[ti][pi] = __builtin_amdgcn_mfma_f32_16x16x32_bf16(pa, xb[pi], ya[ti][pi], 0, 0, 0);
        }
    }
    __syncthreads();
    unsigned short* Ys = (unsigned short*)&PlY[0][0];    // [64][264]
    {
        f32x4 et[4];
        #pragma unroll
        for (int ti = 0; ti < 4; ti++) {
            f32x4 qv = *(const f32x4*)&ql[h][ti * 16 + ko * 4];
            #pragma unroll
            for (int r = 0; r < 4; r++) et[ti][r] = exp2f(qv[r]);
        }
        #pragma unroll
        for (int ti = 0; ti < 4; ti++)
            #pragma unroll
            for (int pi = 0; pi < 2; pi++)
                #pragma unroll
                for (int r = 0; r < 4; r++) {
                    int t = ti * 16 + ko * 4 + r;
                    Ys[t * 264 + h * HD + pi * 16 + m] =
                        f2bfbits(ya[ti][pi][r] + et[ti][r] * ua[ti][pi][r]);
                }
    }
    __syncthreads();
    {
        const int rg = h & 3, nh = h >> 2;
        const int r0 = rg * 16;
        const size_t rowo = (tok0 + r0 + m) * DI;
        float ss = 0.f;
        bf16x8 gb[8];
        #pragma unroll
        for (int kk = 0; kk < 8; kk++) {
            int co = kk * 32 + ko * 8;
            bf16x8 yv = *(const bf16x8*)&Ys[(r0 + m) * 264 + co];
            bf16x8 zv = *(const bf16x8*)(zb + rowo + co);
            #pragma unroll
            for (int j = 0; j < 8; j++) {
                float z = (float)zv[j];
                float g = (float)yv[j] * (z / (1.f + expf(-z)));
                ss += g * g;
                gb[kk][j] = (bf16)g;
            }
        }
        ss += __shfl_xor(ss, 16);
        ss += __shfl_xor(ss, 32);
        const float rs = rsqrtf(ss * (1.0f / DI) + EPSF);
        #pragma unroll
        for (int kk = 0; kk < 8; kk++)
            #pragma unroll
            for (int j = 0; j < 8; j++)
                gb[kk][j] = (bf16)((float)gb[kk][j] * rs);
        const unsigned short* wp = w2f + (size_t)lane * 8;
        f32x4 acc[4] = {};
        #pragma unroll
        for (int kk = 0; kk < 8; kk++) {
            #pragma unroll
            for (int ntl = 0; ntl < 4; ntl++) {
                bf16x8 bfr = *(const bf16x8*)(wp + (((size_t)kk * 8 + nh * 4 + ntl) << 9));
                acc[ntl] = __builtin_amdgcn_mfma_f32_16x16x32_bf16(gb[kk], bfr, acc[ntl], 0, 0, 0);
            }
        }
        #pragma unroll
        for (int ntl = 0; ntl < 4; ntl++) {
            int n = (nh * 4 + ntl) * 16 + m;
            #pragma unroll
            for (int rr = 0; rr < 4; rr++) {
                size_t row = tok0 + r0 + ko * 4 + rr;
                out[row * DM + n] = xin[row * DM + n] + acc[ntl][rr];
            }
        }
    }
}

extern "C" void kernel_launch(void* const* d_in, const int* in_sizes, int n_in,
                              void* d_out, int out_size, void* d_ws, size_t ws_size,
                              hipStream_t stream) {
    const float* x   = (const float*)d_in[0];
    const float* nw  = (const float*)d_in[1];
    const float* w1  = (const float*)d_in[2];
    const float* cw  = (const float*)d_in[3];
    const float* cb  = (const float*)d_in[4];
    const float* dtb = (const float*)d_in[5];
    const float* al  = (const float*)d_in[6];
    const float* Dw  = (const float*)d_in[7];
    const float* gw  = (const float*)d_in[8];
    const float* w2  = (const float*)d_in[9];
    float* out = (float*)d_out;

    float* ws = (float*)d_ws;
    float*  dAp = ws;                                   // 4096 fp32
    float*  dtf = dAp + NB * NH * NC;                   // NTOK*8 fp32
    unsigned short* hst = (unsigned short*)(dtf + (size_t)NTOK * NH); // 64*64*2048 bf16
    unsigned short* zb  = hst + (size_t)NB * NH * NC * 2048;          // NTOK*256
    unsigned short* bcA = zb + (size_t)NTOK * DI;                     // NTOK*128 (B|C tok-major)
    unsigned short* xT  = bcA + (size_t)NTOK * 128;                   // 256*NTOK (x ch-major)
    unsigned short* w1g = xT + (size_t)DI * NTOK;                     // 640*128 frag-packed
    unsigned short* w2f = w1g + (size_t)640 * DM;                     // 128*256 frag-packed

    k_prep<<<(640 * DM + DM * DI + 255) / 256, 256, 0, stream>>>(w1, w2, gw, w1g, w2f);
    k_front<<<NTOK / 64, 512, 0, stream>>>(x, nw, w1, dtb, w1g, cw, cb, al,
                                           zb, dtf, bcA, xT, hst, dAp);
    k_ssm2<<<NB * NH * 8, 256, 0, stream>>>(hst, dAp);
    k_ssd3g<<<NTOK / 64, 512, 0, stream>>>(bcA, xT, dtf, al, hst, Dw, zb, w2f, x, out);
}

// Round 11
// 158.320 us; speedup vs baseline: 1.1379x; 1.0313x over previous
//
#include <hip/hip_runtime.h>

#define DM    128
#define DI    256
#define NH    8
#define HD    32
#define NS    64
#define CDIM  384
#define DPROJ 648
#define LSEQ  4096
#define NB    8
#define NTOK  32768          // NB*LSEQ
#define LC    64             // chunk length
#define NC    64             // chunks per (b,h) sequence
#define EPSF  1e-5f
#define LOG2E 1.4426950408889634f

typedef __bf16 bf16;
typedef bf16  bf16x8 __attribute__((ext_vector_type(8)));
typedef bf16  bf16x4 __attribute__((ext_vector_type(4)));
typedef short short8 __attribute__((ext_vector_type(8)));
typedef float f32x4  __attribute__((ext_vector_type(4)));

__device__ __forceinline__ unsigned short f2bfbits(float f) {
    unsigned int u = __float_as_uint(f);
    unsigned int r = u + 0x7FFFu + ((u >> 16) & 1u);   // RNE
    return (unsigned short)(r >> 16);
}
__device__ __forceinline__ float bfbits2f(unsigned short u) {
    return __uint_as_float(((unsigned int)u) << 16);
}
__device__ __forceinline__ float fast_sigmoid_mul(float x, float v) {
    // v * sigmoid(x) with v_rcp_f32 (≈1ulp fp32; invisible under bf16)
    return v * __builtin_amdgcn_rcpf(1.f + expf(-x));
}

// ---------------- 0. prep: W1 + W2 fragment-packs (gnorm folded into W2) -------
__global__ __launch_bounds__(256) void k_prep(const float* __restrict__ w1,
                                              const float* __restrict__ w2,
                                              const float* __restrict__ gw,
                                              unsigned short* __restrict__ w1g,
                                              unsigned short* __restrict__ w2f) {
    int i = blockIdx.x * 256 + threadIdx.x;
    if (i < 640 * DM) {
        int f = i >> 9, r = i & 511;
        int lane = r >> 3, jj = r & 7;
        int ns = f >> 2, kk = f & 3;
        int n = ns * 16 + (lane & 15), k = kk * 32 + (lane >> 4) * 8 + jj;
        w1g[i] = f2bfbits(w1[(size_t)n * DM + k]);
    } else {
        int j = i - 640 * DM;
        if (j < DM * DI) {
            int f = j >> 9, r = j & 511;
            int lane = r >> 3, jj = r & 7;
            int kk = f >> 3, nt = f & 7;
            int fr = lane & 15, ko = lane >> 4;
            int n = nt * 16 + fr, k = kk * 32 + ko * 8 + jj;
            w2f[j] = f2bfbits(w2[(size_t)n * DI + k] * gw[k]);
        }
    }
}

// ---------------- FRONT: rmsnorm + dt + GEMM1 + conv + ssd1 --------------------
// LDS (59392 B):
//   [0     ..55296)  XT [384][72] bf16 (phase 3+): row=channel, own tokens at
//        col 0..63, halo tokens t0-4..t0-1 at col 64..67.  Row stride 144B =
//        36 dwords -> 16-lane conflict is 2-way (free), was 4-way at 160B.
//        ALIAS (phases 1-2): Xs [64][132] f32 at 0; Hb [16][136] bf16 at 33792;
//        Wd [8][132] f32 at 38144 (all dead before XT is written).
//   [55296..57344)  dts [64][8] f32  (persistent)
//   [57344..59392)  wlh [8][64] f32  (persistent)
// Conv: 384ch x 4 sixteen-token quarters = 1536 tasks over 512 threads (3 each),
// inputs register-staged before barrier (WAR-safe); SiLU uses v_rcp.
__global__ __launch_bounds__(512, 4) void k_front(const float* __restrict__ x,
                                                  const float* __restrict__ nw,
                                                  const float* __restrict__ w1,
                                                  const float* __restrict__ dtb,
                                                  const unsigned short* __restrict__ w1g,
                                                  const float* __restrict__ cw,
                                                  const float* __restrict__ cb,
                                                  const float* __restrict__ alog,
                                                  unsigned short* __restrict__ zb,
                                                  float* __restrict__ dtf,
                                                  unsigned short* __restrict__ bcA,
                                                  unsigned short* __restrict__ xTg,
                                                  unsigned short* __restrict__ hst,
                                                  float* __restrict__ dAp) {
    __shared__ __align__(16) unsigned char SMEM[59392];
    float*          Xs  = (float*)SMEM;                    // [64][132]
    unsigned short* XT  = (unsigned short*)SMEM;           // [384][72] (alias)
    unsigned short* Hb  = (unsigned short*)(SMEM + 33792); // [16][136]
    float*          Wd  = (float*)(SMEM + 38144);          // [8][132]
    float*          dts = (float*)(SMEM + 55296);          // [64][8]
    float*          wlh = (float*)(SMEM + 57344);          // [8][64]
    const int tid = threadIdx.x;
    const int wave = tid >> 6, lane = tid & 63;
    const int t0 = blockIdx.x * 64;
    const int l0 = t0 & (LSEQ - 1);
    // stage dt weight rows (fp32)
    if (tid < 256) {
        int row = tid >> 5, col = (tid & 31) * 4;
        *(float4*)&Wd[row * 132 + col] = *(const float4*)(w1 + (size_t)(640 + row) * DM + col);
    }
    // --- phase 1: rmsnorm 80 rows; halo -> bf16 Hb, own -> fp32 Xs ---
    const float nw0 = nw[lane * 2], nw1 = nw[lane * 2 + 1];
    #pragma unroll
    for (int i = 0; i < 10; i++) {
        int r = wave * 10 + i;
        int tok = t0 + r - 16; if (tok < 0) tok = 0;    // clamp (unused when l0==0)
        const float* xr = x + (size_t)tok * DM + lane * 2;
        float v0 = xr[0], v1 = xr[1];
        float ss = v0 * v0 + v1 * v1;
        #pragma unroll
        for (int o = 32; o; o >>= 1) ss += __shfl_xor(ss, o);
        float rs = rsqrtf(ss * (1.0f / DM) + EPSF);
        float o0 = v0 * rs * nw0, o1 = v1 * rs * nw1;
        if (r < 16) {
            ushort2 hb; hb.x = f2bfbits(o0); hb.y = f2bfbits(o1);
            *(ushort2*)&Hb[r * 136 + lane * 2] = hb;
        } else {
            Xs[(r - 16) * 132 + lane * 2]     = o0;
            Xs[(r - 16) * 132 + lane * 2 + 1] = o1;
        }
    }
    __syncthreads();
    // --- phase 2a: dt (fp32 exact), 8 own rows per wave ---
    {
        const int h = lane >> 3, ks = lane & 7;
        const float dtbh = dtb[h];
        #pragma unroll
        for (int i = 0; i < 8; i++) {
            int rw = wave * 8 + i;
            float acc = 0.f;
            #pragma unroll
            for (int q = 0; q < 4; q++) {
                float4 xv = *(const float4*)&Xs[rw * 132 + ks * 16 + q * 4];
                float4 wv = *(const float4*)&Wd[h * 132 + ks * 16 + q * 4];
                acc = fmaf(xv.x, wv.x, acc); acc = fmaf(xv.y, wv.y, acc);
                acc = fmaf(xv.z, wv.z, acc); acc = fmaf(xv.w, wv.w, acc);
            }
            acc += __shfl_xor(acc, 1);
            acc += __shfl_xor(acc, 2);
            acc += __shfl_xor(acc, 4);
            if (ks == 0) {
                float v = acc + dtbh;
                float sp = (v > 20.f) ? v : log1pf(expf(v));
                dtf[(size_t)(t0 + rw) * NH + h] = sp;
                dts[rw * NH + h] = sp;
            }
        }
    }
    // --- phase 2b: bf16 A-frags (own 2 from fp32 Xs, halo 1 from bf16 Hb) ---
    const int wm = wave >> 2, wn = wave & 3;
    const int fr = lane & 15, ko = lane >> 4;
    bf16x8 a0[4], a1[4], ah[4];
    #pragma unroll
    for (int kk = 0; kk < 4; kk++) {
        const float* s0 = &Xs[(wm * 32 + fr) * 132 + kk * 32 + ko * 8];
        const float* s1 = &Xs[(wm * 32 + 16 + fr) * 132 + kk * 32 + ko * 8];
        bf16x8 f0, f1;
        #pragma unroll
        for (int j = 0; j < 8; j++) { f0[j] = (bf16)s0[j]; f1[j] = (bf16)s1[j]; }
        a0[kk] = f0; a1[kk] = f1;
        ah[kk] = *(const bf16x8*)&Hb[fr * 136 + kk * 32 + ko * 8];
    }
    __syncthreads();                 // Xs/Hb/Wd dead -> XT may be written
    // --- phase 3 GEMM: z -> global, xBC -> XT (ch-major) ---
    for (int i = 0; i < 10; i++) {
        int f = i * 4 + wn;
        const unsigned short* wb = w1g + (((size_t)f * 4) << 9) + lane * 8;
        f32x4 acc0 = {}, acc1 = {}, accH = {};
        #pragma unroll
        for (int kk = 0; kk < 4; kk++) {
            bf16x8 bfr = *(const bf16x8*)(wb + ((size_t)kk << 9));
            acc0 = __builtin_amdgcn_mfma_f32_16x16x32_bf16(a0[kk], bfr, acc0, 0, 0, 0);
            acc1 = __builtin_amdgcn_mfma_f32_16x16x32_bf16(a1[kk], bfr, acc1, 0, 0, 0);
            if (i >= 4 && wm == 0)
                accH = __builtin_amdgcn_mfma_f32_16x16x32_bf16(ah[kk], bfr, accH, 0, 0, 0);
        }
        if (i < 4) {                     // z frag -> global
            int n = f * 16 + fr;
            #pragma unroll
            for (int rr = 0; rr < 4; rr++) {
                zb[(size_t)(t0 + wm * 32 + ko * 4 + rr) * DI + n]      = f2bfbits(acc0[rr]);
                zb[(size_t)(t0 + wm * 32 + 16 + ko * 4 + rr) * DI + n] = f2bfbits(acc1[rr]);
            }
        } else {                         // xBC frag -> XT, 8B stores
            int cc = f * 16 + fr - 256;
            bf16x4 p0, p1;
            #pragma unroll
            for (int rr = 0; rr < 4; rr++) { p0[rr] = (bf16)acc0[rr]; p1[rr] = (bf16)acc1[rr]; }
            *(bf16x4*)&XT[cc * 72 + wm * 32 + ko * 4]      = p0;
            *(bf16x4*)&XT[cc * 72 + wm * 32 + 16 + ko * 4] = p1;
            if (wm == 0 && ko == 3) {    // halo rows 12..15 = tokens t0-4..t0-1
                bf16x4 pH;
                #pragma unroll
                for (int rr = 0; rr < 4; rr++) pH[rr] = (bf16)accH[rr];
                *(bf16x4*)&XT[cc * 72 + 64] = pH;
            }
        }
    }
    __syncthreads();
    // --- phase 4a: conv input staging (registers; WAR-safe across barrier) ---
    int tch[3], tq[3];
    bf16x8 ci[3][2];
    bf16x4 chh[3];
    #pragma unroll
    for (int k = 0; k < 3; k++) {
        int task = tid + k * 512;
        int q = task / 384, ch = task - q * 384;
        tch[k] = ch; tq[k] = q;
        ci[k][0] = *(const bf16x8*)&XT[ch * 72 + q * 16];
        ci[k][1] = *(const bf16x8*)&XT[ch * 72 + q * 16 + 8];
        chh[k] = (q == 0)
            ? *(const bf16x4*)&XT[ch * 72 + 64]
            : *(const bf16x4*)&XT[ch * 72 + q * 16 - 4];
    }
    __syncthreads();
    // --- phase 4b: conv K=4 + SiLU compute + writeback (3 independent chains) --
    #pragma unroll
    for (int k = 0; k < 3; k++) {
        const int ch = tch[k], q = tq[k];
        float4 wv = *(const float4*)(cw + ch * 4);
        float bias = cb[ch];
        float h1 = (float)chh[k][3], h2 = (float)chh[k][2], h3 = (float)chh[k][1];
        if (q == 0 && !l0) { h1 = 0.f; h2 = 0.f; h3 = 0.f; }
        #pragma unroll
        for (int u = 0; u < 2; u++) {
            bf16x8 iv = ci[k][u];
            bf16x8 ov;
            #pragma unroll
            for (int j = 0; j < 8; j++) {
                float x0 = (float)iv[j];
                float acc = bias;
                acc = fmaf(x0, wv.w, acc);
                acc = fmaf(h1, wv.z, acc);
                acc = fmaf(h2, wv.y, acc);
                acc = fmaf(h3, wv.x, acc);
                float s = fast_sigmoid_mul(acc, acc);
                ov[j] = (bf16)s;
                if (ch >= 256)
                    bcA[(size_t)(t0 + q * 16 + u * 8 + j) * 128 + (ch - 256)] = f2bfbits(s);
                h3 = h2; h2 = h1; h1 = x0;
            }
            *(bf16x8*)&XT[ch * 72 + q * 16 + u * 8] = ov;
        }
    }
    __syncthreads();
    // --- phase 5: xT writeout (coalesced b128) ---
    {
        int idx = tid;
        #pragma unroll
        for (int it = 0; it < 4; it++, idx += 512) {
            int row = idx >> 3, tc = (idx & 7) * 8;
            *(short8*)(xTg + (size_t)row * NTOK + t0 + tc) = *(const short8*)&XT[row * 72 + tc];
        }
    }
    // --- phase 6: ssd1, wave = head ---
    {
        const int h = wave;
        const int b = blockIdx.x >> 6, c = blockIdx.x & 63;
        const int bh = b * NH + h;
        const float A = -expf(alog[h]);
        float dt = dts[lane * NH + h];
        float q = dt * A * LOG2E;
        #pragma unroll
        for (int o = 1; o <= 32; o <<= 1) {
            float tmp = __shfl_up(q, o);
            if (lane >= o) q += tmp;
        }
        float qL = __shfl(q, 63);
        wlh[h * 64 + lane] = exp2f(qL - q) * dt;   // intra-wave LDS: no barrier
        if (lane == 0) dAp[(size_t)bh * NC + c] = exp2f(qL);
        const int m = lane & 15;
        f32x4 hacc[4][2] = {};
        #pragma unroll
        for (int kh = 0; kh < 2; kh++) {
            bf16x8 xb[2];
            #pragma unroll
            for (int pi = 0; pi < 2; pi++)
                xb[pi] = *(const bf16x8*)&XT[(h * HD + pi * 16 + m) * 72 + kh * 32 + ko * 8];
            f32x4 w0 = *(const f32x4*)&wlh[h * 64 + kh * 32 + ko * 8];
            f32x4 w1v = *(const f32x4*)&wlh[h * 64 + kh * 32 + ko * 8 + 4];
            #pragma unroll
            for (int ni = 0; ni < 4; ni++) {
                bf16x8 bv = *(const bf16x8*)&XT[(256 + ni * 16 + m) * 72 + kh * 32 + ko * 8];
                bf16x8 af;
                #pragma unroll
                for (int j = 0; j < 4; j++) af[j] = (bf16)((float)bv[j] * w0[j]);
                #pragma unroll
                for (int j = 0; j < 4; j++) af[4 + j] = (bf16)((float)bv[4 + j] * w1v[j]);
                #pragma unroll
                for (int pi = 0; pi < 2; pi++)
                    hacc[ni][pi] = __builtin_amdgcn_mfma_f32_16x16x32_bf16(af, xb[pi], hacc[ni][pi], 0, 0, 0);
            }
        }
        unsigned short* hb = hst + (((size_t)bh * NC + c) << 11);
        #pragma unroll
        for (int ni = 0; ni < 4; ni++)
            #pragma unroll
            for (int pi = 0; pi < 2; pi++) {
                bf16x4 pv;
                #pragma unroll
                for (int r = 0; r < 4; r++) pv[r] = (bf16)hacc[ni][pi][r];
                *(bf16x4*)(hb + (pi * 16 + m) * 64 + ni * 16 + ko * 4) = pv;
            }
    }
}

// ---------------- 5b. SSM pass 2: scan, 1 bh/block, depth-4 load pipeline ------
__global__ __launch_bounds__(256) void k_ssm2(unsigned short* __restrict__ hst,
                                              const float* __restrict__ dAp) {
    __shared__ float dl[NC];
    const int bh = blockIdx.x >> 3, seg = blockIdx.x & 7;
    const int s = seg * 256 + threadIdx.x;
    if (threadIdx.x < NC) dl[threadIdx.x] = dAp[(size_t)bh * NC + threadIdx.x];
    __syncthreads();
    unsigned short* p = hst + ((size_t)bh * NC << 11) + s;
    float r = 0.f;
    float v0 = bfbits2f(p[0]);
    float v1 = bfbits2f(p[(size_t)1 << 11]);
    float v2 = bfbits2f(p[(size_t)2 << 11]);
    float v3 = bfbits2f(p[(size_t)3 << 11]);
    for (int c = 0; c < NC; c += 4) {
        float t;
        t = v0; if (c + 4 < NC) v0 = bfbits2f(p[(size_t)(c + 4) << 11]);
        p[(size_t)c << 11] = f2bfbits(r);       r = fmaf(r, dl[c], t);
        t = v1; if (c + 5 < NC) v1 = bfbits2f(p[(size_t)(c + 5) << 11]);
        p[(size_t)(c + 1) << 11] = f2bfbits(r); r = fmaf(r, dl[c + 1], t);
        t = v2; if (c + 6 < NC) v2 = bfbits2f(p[(size_t)(c + 6) << 11]);
        p[(size_t)(c + 2) << 11] = f2bfbits(r); r = fmaf(r, dl[c + 2], t);
        t = v3; if (c + 7 < NC) v3 = bfbits2f(p[(size_t)(c + 7) << 11]);
        p[(size_t)(c + 3) << 11] = f2bfbits(r); r = fmaf(r, dl[c + 3], t);
    }
}

// ---------------- 5c+6+7. fused SSD pass 3 + gate + GEMM2 + residual -----------
__global__ __launch_bounds__(512, 2) void k_ssd3g(const unsigned short* __restrict__ bcA,
                                                  const unsigned short* __restrict__ xT,
                                                  const float* __restrict__ dtf,
                                                  const float* __restrict__ alog,
                                                  const unsigned short* __restrict__ hst,
                                                  const float* __restrict__ Dw,
                                                  const unsigned short* __restrict__ zb,
                                                  const unsigned short* __restrict__ w2f,
                                                  const float* __restrict__ xin,
                                                  float* __restrict__ out) {
    __shared__ __align__(16) unsigned short BC[64][136];   // B|C chunk, all heads
    __shared__ __align__(16) bf16 PlY[NH][64 * 40];        // per-wave P half; alias: Ys[64][264]
    __shared__ float ql[NH][64];
    __shared__ float dl[NH][64];
    const int tid = threadIdx.x;
    const int b = blockIdx.x >> 6, c = blockIdx.x & 63;
    const int t0 = blockIdx.x * 64;
    const size_t tok0 = (size_t)t0;
    {
        int idx = tid;
        #pragma unroll
        for (int it = 0; it < 2; it++, idx += 512) {
            int tok = idx >> 4, c8 = (idx & 15) * 8;
            *(short8*)&BC[tok][c8] = *(const short8*)(bcA + (tok0 + tok) * 128 + c8);
        }
    }
    __syncthreads();
    const int h = tid >> 6, lane = tid & 63;
    const int bh = b * NH + h;
    const float A = -expf(alog[h]);
    const float Dh = Dw[h];
    float dt = dtf[(tok0 + lane) * NH + h];
    float q = dt * A * LOG2E;
    #pragma unroll
    for (int o = 1; o <= 32; o <<= 1) {
        float tmp = __shfl_up(q, o);
        if (lane >= o) q += tmp;
    }
    ql[h][lane] = q;                           // intra-wave LDS, no barrier
    dl[h][lane] = dt;
    const int m = lane & 15, ko = lane >> 4;
    bf16* Pw = &PlY[h][0];
    bf16x8 cf[4][2];
    #pragma unroll
    for (int ti = 0; ti < 4; ti++)
        #pragma unroll
        for (int kh = 0; kh < 2; kh++)
            cf[ti][kh] = *(const bf16x8*)&BC[ti * 16 + m][64 + kh * 32 + ko * 8];
    float qt[4];
    #pragma unroll
    for (int ti = 0; ti < 4; ti++) qt[ti] = ql[h][ti * 16 + m];
    const size_t hbase = ((size_t)bh * NC + c) << 11;
    f32x4 ya[4][2] = {}, ua[4][2] = {};
    #pragma unroll
    for (int kh = 0; kh < 2; kh++) {
        bf16x8 hb2[2];
        #pragma unroll
        for (int pi = 0; pi < 2; pi++)
            hb2[pi] = *(const bf16x8*)(hst + hbase + (pi * 16 + m) * 64 + kh * 32 + ko * 8);
        #pragma unroll
        for (int ti = 0; ti < 4; ti++)
            #pragma unroll
            for (int pi = 0; pi < 2; pi++)
                ua[ti][pi] = __builtin_amdgcn_mfma_f32_16x16x32_bf16(cf[ti][kh], hb2[pi], ua[ti][pi], 0, 0, 0);
    }
    #pragma unroll
    for (int sh = 0; sh < 2; sh++) {
        f32x4 gth[4][2] = {};
        #pragma unroll
        for (int kh = 0; kh < 2; kh++) {
            bf16x8 bfg[2];
            #pragma unroll
            for (int sj = 0; sj < 2; sj++)
                bfg[sj] = *(const bf16x8*)&BC[(sh * 2 + sj) * 16 + m][kh * 32 + ko * 8];
            #pragma unroll
            for (int ti = 0; ti < 4; ti++)
                #pragma unroll
                for (int sj = 0; sj < 2; sj++)
                    gth[ti][sj] = __builtin_amdgcn_mfma_f32_16x16x32_bf16(bfg[sj], cf[ti][kh], gth[ti][sj], 0, 0, 0);
        }
        #pragma unroll
        for (int sj = 0; sj < 2; sj++) {
            const int si = sh * 2 + sj;
            f32x4 qs = *(const f32x4*)&ql[h][si * 16 + ko * 4];
            f32x4 ds = *(const f32x4*)&dl[h][si * 16 + ko * 4];
            #pragma unroll
            for (int ti = 0; ti < 4; ti++) {
                bf16x4 pv = {};
                if (si <= ti) {
                    const int t = ti * 16 + m;
                    #pragma unroll
                    for (int r = 0; r < 4; r++) {
                        int s = si * 16 + ko * 4 + r;
                        float p = 0.f;
                        if (s <= t) {
                            p = exp2f(qt[ti] - qs[r]) * ds[r] * gth[ti][sj][r];
                            if (s == t) p += Dh;
                        }
                        pv[r] = (bf16)p;
                    }
                }
                *(bf16x4*)&Pw[(ti * 16 + m) * 40 + sj * 16 + ko * 4] = pv;
            }
        }
        bf16x8 xb[2];
        #pragma unroll
        for (int pi = 0; pi < 2; pi++)
            xb[pi] = *(const bf16x8*)(xT + (size_t)(h * HD + pi * 16 + m) * NTOK + tok0 + sh * 32 + ko * 8);
        #pragma unroll
        for (int ti = 0; ti < 4; ti++) {
            bf16x8 pa = *(const bf16x8*)&Pw[(ti * 16 + m) * 40 + ko * 8];
            #pragma unroll
            for (int pi = 0; pi < 2; pi++)
                ya[ti][pi] = __builtin_amdgcn_mfma_f32_16x16x32_bf16(pa, xb[pi], ya[ti][pi], 0, 0, 0);
        }
    }
    __syncthreads();
    unsigned short* Ys = (unsigned short*)&PlY[0][0];    // [64][264]
    {
        f32x4 et[4];
        #pragma unroll
        for (int ti = 0; ti < 4; ti++) {
            f32x4 qv = *(const f32x4*)&ql[h][ti * 16 + ko * 4];
            #pragma unroll
            for (int r = 0; r < 4; r++) et[ti][r] = exp2f(qv[r]);
        }
        #pragma unroll
        for (int ti = 0; ti < 4; ti++)
            #pragma unroll
            for (int pi = 0; pi < 2; pi++)
                #pragma unroll
                for (int r = 0; r < 4; r++) {
                    int t = ti * 16 + ko * 4 + r;
                    Ys[t * 264 + h * HD + pi * 16 + m] =
                        f2bfbits(ya[ti][pi][r] + et[ti][r] * ua[ti][pi][r]);
                }
    }
    __syncthreads();
    {
        const int rg = h & 3, nh = h >> 2;
        const int r0 = rg * 16;
        const size_t rowo = (tok0 + r0 + m) * DI;
        float ss = 0.f;
        bf16x8 gb[8];
        #pragma unroll
        for (int kk = 0; kk < 8; kk++) {
            int co = kk * 32 + ko * 8;
            bf16x8 yv = *(const bf16x8*)&Ys[(r0 + m) * 264 + co];
            bf16x8 zv = *(const bf16x8*)(zb + rowo + co);
            #pragma unroll
            for (int j = 0; j < 8; j++) {
                float z = (float)zv[j];
                float g = (float)yv[j] * fast_sigmoid_mul(z, z);
                ss += g * g;
                gb[kk][j] = (bf16)g;
            }
        }
        ss += __shfl_xor(ss, 16);
        ss += __shfl_xor(ss, 32);
        const float rs = rsqrtf(ss * (1.0f / DI) + EPSF);
        #pragma unroll
        for (int kk = 0; kk < 8; kk++)
            #pragma unroll
            for (int j = 0; j < 8; j++)
                gb[kk][j] = (bf16)((float)gb[kk][j] * rs);
        const unsigned short* wp = w2f + (size_t)lane * 8;
        f32x4 acc[4] = {};
        #pragma unroll
        for (int kk = 0; kk < 8; kk++) {
            #pragma unroll
            for (int ntl = 0; ntl < 4; ntl++) {
                bf16x8 bfr = *(const bf16x8*)(wp + (((size_t)kk * 8 + nh * 4 + ntl) << 9));
                acc[ntl] = __builtin_amdgcn_mfma_f32_16x16x32_bf16(gb[kk], bfr, acc[ntl], 0, 0, 0);
            }
        }
        #pragma unroll
        for (int ntl = 0; ntl < 4; ntl++) {
            int n = (nh * 4 + ntl) * 16 + m;
            #pragma unroll
            for (int rr = 0; rr < 4; rr++) {
                size_t row = tok0 + r0 + ko * 4 + rr;
                out[row * DM + n] = xin[row * DM + n] + acc[ntl][rr];
            }
        }
    }
}

extern "C" void kernel_launch(void* const* d_in, const int* in_sizes, int n_in,
                              void* d_out, int out_size, void* d_ws, size_t ws_size,
                              hipStream_t stream) {
    const float* x   = (const float*)d_in[0];
    const float* nw  = (const float*)d_in[1];
    const float* w1  = (const float*)d_in[2];
    const float* cw  = (const float*)d_in[3];
    const float* cb  = (const float*)d_in[4];
    const float* dtb = (const float*)d_in[5];
    const float* al  = (const float*)d_in[6];
    const float* Dw  = (const float*)d_in[7];
    const float* gw  = (const float*)d_in[8];
    const float* w2  = (const float*)d_in[9];
    float* out = (float*)d_out;

    float* ws = (float*)d_ws;
    float*  dAp = ws;                                   // 4096 fp32
    float*  dtf = dAp + NB * NH * NC;                   // NTOK*8 fp32
    unsigned short* hst = (unsigned short*)(dtf + (size_t)NTOK * NH); // 64*64*2048 bf16
    unsigned short* zb  = hst + (size_t)NB * NH * NC * 2048;          // NTOK*256
    unsigned short* bcA = zb + (size_t)NTOK * DI;                     // NTOK*128 (B|C tok-major)
    unsigned short* xT  = bcA + (size_t)NTOK * 128;                   // 256*NTOK (x ch-major)
    unsigned short* w1g = xT + (size_t)DI * NTOK;                     // 640*128 frag-packed
    unsigned short* w2f = w1g + (size_t)640 * DM;                     // 128*256 frag-packed

    k_prep<<<(640 * DM + DM * DI + 255) / 256, 256, 0, stream>>>(w1, w2, gw, w1g, w2f);
    k_front<<<NTOK / 64, 512, 0, stream>>>(x, nw, w1, dtb, w1g, cw, cb, al,
                                           zb, dtf, bcA, xT, hst, dAp);
    k_ssm2<<<NB * NH * 8, 256, 0, stream>>>(hst, dAp);
    k_ssd3g<<<NTOK / 64, 512, 0, stream>>>(bcA, xT, dtf, al, hst, Dw, zb, w2f, x, out);
}